// Round 2
// baseline (1603.208 us; speedup 1.0000x reference)
//
#include <hip/hip_runtime.h>

typedef __attribute__((ext_vector_type(8))) short bf16x8;
typedef __attribute__((ext_vector_type(4))) float f32x4;
typedef __attribute__((ext_vector_type(4))) unsigned int u32x4;

constexpr int B_ = 4, L_ = 4096, S_ = 4096, D_ = 2048, H_ = 16, HD_ = 128;
constexpr int BM = 128, BN = 128, BK = 64, LDSS = BK + 8; // 72

__device__ __forceinline__ unsigned short f2bf(float f) {
    unsigned int u = __builtin_bit_cast(unsigned int, f);
    return (unsigned short)((u + 0x7fffu + ((u >> 16) & 1u)) >> 16);
}
__device__ __forceinline__ float bf2f(unsigned short h) {
    unsigned int u = ((unsigned int)h) << 16;
    return __builtin_bit_cast(float, u);
}
__device__ __forceinline__ unsigned long long pack4(float a, float b, float c, float d) {
    return (unsigned long long)f2bf(a) | ((unsigned long long)f2bf(b) << 16)
         | ((unsigned long long)f2bf(c) << 32) | ((unsigned long long)f2bf(d) << 48);
}
__device__ __forceinline__ float featmap(float x) {
    return x > 0.f ? x + 1.f : __expf(x);
}

// C = A @ B^T with A [M,K] row-major, B [N,K] row-major (weights are [out,in]).
// MODE 0: A=query(f32). bn<16 -> C1=q_feat=featmap(.); bn>=16 -> B=Bw2(Wg), C2=gate=sigmoid(.+bias)
// MODE 1: A=kv(f32), B=Wkv[4096,2048]. bn<16 -> k: featmap, TRANSPOSED store to C1[bh][d][s];
//         bn>=16 -> v: passthrough, transposed store to C2.
// MODE 2: A=Ah(bf16)=y, B=Wo, plain fp32 output Cf.
template<int MODE>
__global__ __launch_bounds__(256) void gemm_bt(
    const float* __restrict__ Af, const unsigned short* __restrict__ Ah,
    const float* __restrict__ Bw, const float* __restrict__ Bw2,
    unsigned short* __restrict__ C1, unsigned short* __restrict__ C2,
    float* __restrict__ Cf, const float* __restrict__ bias)
{
    __shared__ unsigned short smem[BM * LDSS + BN * LDSS];
    unsigned short* As = smem;
    unsigned short* Bs = smem + BM * LDSS;
    const int tid = threadIdx.x;
    const int bm = blockIdx.x, bn = blockIdx.y;
    const int row0 = bm * BM;
    const int lane = tid & 63, w = tid >> 6;
    const int wm = (w >> 1) * 64, wn = (w & 1) * 64;
    const int lr = lane & 15, lk = (lane >> 4) * 8;
    const bool second = bn >= H_;
    const float* Bp = (MODE == 0 && second) ? Bw2 : Bw;
    const int bcol = (MODE == 0 && second) ? (bn - H_) * BN : bn * BN;

    f32x4 acc[4][4] = {};

    for (int k0 = 0; k0 < D_; k0 += BK) {
        if (MODE == 2) {
            #pragma unroll
            for (int i = 0; i < 4; i++) {
                int idx = tid + i * 256;
                int r = idx >> 3, c = (idx & 7) * 8;
                *(u32x4*)&As[r * LDSS + c] =
                    *(const u32x4*)&Ah[(size_t)(row0 + r) * D_ + k0 + c];
            }
        } else {
            #pragma unroll
            for (int i = 0; i < 8; i++) {
                int idx = tid + i * 256;
                int r = idx >> 4, c = (idx & 15) * 4;
                const float4 v = *(const float4*)&Af[(size_t)(row0 + r) * D_ + k0 + c];
                *(unsigned long long*)&As[r * LDSS + c] = pack4(v.x, v.y, v.z, v.w);
            }
        }
        #pragma unroll
        for (int i = 0; i < 8; i++) {
            int idx = tid + i * 256;
            int r = idx >> 4, c = (idx & 15) * 4;
            const float4 v = *(const float4*)&Bp[(size_t)(bcol + r) * D_ + k0 + c];
            *(unsigned long long*)&Bs[r * LDSS + c] = pack4(v.x, v.y, v.z, v.w);
        }
        __syncthreads();
        #pragma unroll
        for (int ks = 0; ks < BK; ks += 32) {
            bf16x8 av[4], bv[4];
            #pragma unroll
            for (int mi = 0; mi < 4; mi++)
                av[mi] = *(const bf16x8*)&As[(wm + mi * 16 + lr) * LDSS + ks + lk];
            #pragma unroll
            for (int ni = 0; ni < 4; ni++)
                bv[ni] = *(const bf16x8*)&Bs[(wn + ni * 16 + lr) * LDSS + ks + lk];
            #pragma unroll
            for (int mi = 0; mi < 4; mi++)
                #pragma unroll
                for (int ni = 0; ni < 4; ni++)
                    acc[mi][ni] = __builtin_amdgcn_mfma_f32_16x16x32_bf16(
                        av[mi], bv[ni], acc[mi][ni], 0, 0, 0);
        }
        __syncthreads();
    }

    const int rb = (lane >> 4) * 4;
    if (MODE == 1) {
        // transpose 128x128 tile through LDS, write [bh][d][s] coalesced
        unsigned short* TT = smem;          // 128*136 = 17408 <= 18432 (reuse As+Bs)
        const int TP = HD_ + 8;             // 136
        const int isv = second ? 1 : 0;
        const int h2 = bn & (H_ - 1);
        #pragma unroll
        for (int mi = 0; mi < 4; mi++) {
            #pragma unroll
            for (int ni = 0; ni < 4; ni++) {
                float x0 = acc[mi][ni][0], x1 = acc[mi][ni][1];
                float x2 = acc[mi][ni][2], x3 = acc[mi][ni][3];
                if (!isv) {
                    x0 = featmap(x0); x1 = featmap(x1);
                    x2 = featmap(x2); x3 = featmap(x3);
                }
                *(unsigned long long*)&TT[(wn + ni * 16 + lr) * TP + wm + mi * 16 + rb]
                    = pack4(x0, x1, x2, x3);
            }
        }
        __syncthreads();
        const int b = row0 >> 12;           // 4096 rows per batch
        const int sl0 = row0 & (S_ - 1);
        unsigned short* dst = (isv ? C2 : C1) + (size_t)(b * H_ + h2) * HD_ * S_;
        #pragma unroll
        for (int i = 0; i < 8; i++) {
            int idx = tid + 256 * i;
            int d = idx >> 4, sc = (idx & 15) * 8;
            *(u32x4*)&dst[(size_t)d * S_ + sl0 + sc] = *(const u32x4*)&TT[d * TP + sc];
        }
        return;
    }
    #pragma unroll
    for (int mi = 0; mi < 4; mi++) {
        #pragma unroll
        for (int ni = 0; ni < 4; ni++) {
            #pragma unroll
            for (int r = 0; r < 4; r++) {
                const size_t gr = (size_t)(row0 + wm + mi * 16 + rb + r);
                const int gc = bcol + wn + ni * 16 + lr;
                float x = acc[mi][ni][r];
                if (MODE == 0) {
                    if (!second) {
                        C1[gr * D_ + gc] = f2bf(featmap(x));
                    } else {
                        float t = x + bias[gc];
                        C2[gr * D_ + gc] = f2bf(1.f / (1.f + __expf(-t)));
                    }
                } else {
                    Cf[gr * D_ + gc] = x;
                }
            }
        }
    }
}

// kv_summary partials: per (s-chunk cx, bh): part[cx][bh][d][e] = sum_{s in chunk} k[s,d]*v[s,e]
// inputs are transposed [bh][d][s] so LDS staging is fully vectorized.
__global__ __launch_bounds__(256) void kvsum_part(
    const unsigned short* __restrict__ kT, const unsigned short* __restrict__ vT,
    float* __restrict__ part, float* __restrict__ ksum_part)
{
    __shared__ unsigned short kA[HD_ * LDSS];
    __shared__ unsigned short vB[HD_ * LDSS];
    __shared__ float red[HD_ * 8];
    const int tid = threadIdx.x;
    const int cx = blockIdx.x, bh = blockIdx.y;
    const int lane = tid & 63, w = tid >> 6;
    const int wm = (w >> 1) * 64, wn = (w & 1) * 64;
    const int lr = lane & 15, lk = (lane >> 4) * 8;
    const unsigned short* kb = kT + (size_t)bh * HD_ * S_;
    const unsigned short* vb = vT + (size_t)bh * HD_ * S_;
    f32x4 acc[4][4] = {};
    float ksl[4] = {0.f, 0.f, 0.f, 0.f};
    const int chunk = S_ / 8;
    const int s_begin = cx * chunk;
    for (int s0 = s_begin; s0 < s_begin + chunk; s0 += 64) {
        #pragma unroll
        for (int i = 0; i < 4; i++) {
            int idx = tid + i * 256;
            int d = idx >> 3, sc = (idx & 7) * 8;
            u32x4 kk = *(const u32x4*)&kb[(size_t)d * S_ + s0 + sc];
            *(u32x4*)&kA[d * LDSS + sc] = kk;
            unsigned short t8[8];
            *(u32x4*)t8 = kk;
            float ss = 0.f;
            #pragma unroll
            for (int j = 0; j < 8; j++) ss += bf2f(t8[j]);
            ksl[i] += ss;
            *(u32x4*)&vB[d * LDSS + sc] = *(const u32x4*)&vb[(size_t)d * S_ + s0 + sc];
        }
        __syncthreads();
        #pragma unroll
        for (int ks = 0; ks < 64; ks += 32) {
            bf16x8 av[4], bv[4];
            #pragma unroll
            for (int mi = 0; mi < 4; mi++)
                av[mi] = *(const bf16x8*)&kA[(wm + mi * 16 + lr) * LDSS + ks + lk];
            #pragma unroll
            for (int ni = 0; ni < 4; ni++)
                bv[ni] = *(const bf16x8*)&vB[(wn + ni * 16 + lr) * LDSS + ks + lk];
            #pragma unroll
            for (int mi = 0; mi < 4; mi++)
                #pragma unroll
                for (int ni = 0; ni < 4; ni++)
                    acc[mi][ni] = __builtin_amdgcn_mfma_f32_16x16x32_bf16(
                        av[mi], bv[ni], acc[mi][ni], 0, 0, 0);
        }
        __syncthreads();
    }
    // k_sum partial: thread covered d = tid>>3 + 32*i, 8 s-values per stage
    #pragma unroll
    for (int i = 0; i < 4; i++) red[((tid >> 3) + 32 * i) * 8 + (tid & 7)] = ksl[i];
    __syncthreads();
    if (tid < HD_) {
        float s = 0.f;
        #pragma unroll
        for (int j = 0; j < 8; j++) s += red[tid * 8 + j];
        ksum_part[(size_t)cx * (64 * HD_) + bh * HD_ + tid] = s;
    }
    const int rb = (lane >> 4) * 4;
    float* pp = part + ((size_t)cx * 64 + bh) * (HD_ * HD_);
    #pragma unroll
    for (int mi = 0; mi < 4; mi++)
        #pragma unroll
        for (int ni = 0; ni < 4; ni++)
            #pragma unroll
            for (int r = 0; r < 4; r++)
                pp[(wm + mi * 16 + rb + r) * HD_ + wn + ni * 16 + lr] = acc[mi][ni][r];
}

// reduce 8 partials -> kvsT[bh][e][d] (bf16, transposed so attn B-frags are contiguous) + ksum
__global__ __launch_bounds__(256) void kvs_reduce(
    const float* __restrict__ part, unsigned short* __restrict__ kvsT,
    const float* __restrict__ ksum_part, float* __restrict__ ksum)
{
    const int idx = blockIdx.x * 256 + threadIdx.x;
    const int e = idx & 127, d2 = (idx >> 7) & 127, bh = idx >> 14;
    float s = 0.f;
    #pragma unroll
    for (int cx = 0; cx < 8; cx++)
        s += part[((size_t)cx * 64 + bh) * 16384 + d2 * 128 + e];
    kvsT[((size_t)bh * 128 + e) * 128 + d2] = f2bf(s);
    if (idx < 64 * 128) {
        float t = 0.f;
        #pragma unroll
        for (int cx = 0; cx < 8; cx++) t += ksum_part[cx * 8192 + idx];
        ksum[idx] = t;
    }
}

// attn = (q @ kvs) * z * gate -> y (bf16)
__global__ __launch_bounds__(256) void attn_kernel(
    const unsigned short* __restrict__ qf, const unsigned short* __restrict__ kvsT,
    const float* __restrict__ ksum, const unsigned short* __restrict__ gate,
    unsigned short* __restrict__ y)
{
    __shared__ unsigned short qs[128 * 136];
    __shared__ unsigned short bs[128 * LDSS];
    __shared__ float zl[128];
    const int tid = threadIdx.x;
    const int l0 = blockIdx.x * 128;
    const int h = blockIdx.y, b = blockIdx.z;
    const int bh = b * H_ + h;
    const int lane = tid & 63, w = tid >> 6;
    const int wm = (w >> 1) * 64, wn = (w & 1) * 64;
    const int lr = lane & 15, lk = (lane >> 4) * 8;
    const size_t qbase = (size_t)b * L_ * D_ + (size_t)h * HD_;
    #pragma unroll
    for (int i = 0; i < 8; i++) {
        int idx = tid + i * 256;
        int r = idx >> 4, c = (idx & 15) * 8;
        *(u32x4*)&qs[r * 136 + c] = *(const u32x4*)&qf[qbase + (size_t)(l0 + r) * D_ + c];
    }
    __syncthreads();
    if (tid < 128) {
        const float* kp = ksum + bh * HD_;
        float sden = 0.f;
        #pragma unroll 4
        for (int d2 = 0; d2 < HD_; d2++) sden += bf2f(qs[tid * 136 + d2]) * kp[d2];
        zl[tid] = 1.f / (sden + 1e-6f);
    }
    f32x4 acc[4][4] = {};
    for (int kc = 0; kc < 2; kc++) {
        #pragma unroll
        for (int i = 0; i < 4; i++) {
            int idx = tid + i * 256;
            int e = idx >> 3, dc = (idx & 7) * 8;
            *(u32x4*)&bs[e * LDSS + dc] =
                *(const u32x4*)&kvsT[((size_t)bh * 128 + e) * 128 + kc * 64 + dc];
        }
        __syncthreads();
        #pragma unroll
        for (int ks = 0; ks < 64; ks += 32) {
            bf16x8 av[4], bv[4];
            #pragma unroll
            for (int mi = 0; mi < 4; mi++)
                av[mi] = *(const bf16x8*)&qs[(wm + mi * 16 + lr) * 136 + kc * 64 + ks + lk];
            #pragma unroll
            for (int ni = 0; ni < 4; ni++)
                bv[ni] = *(const bf16x8*)&bs[(wn + ni * 16 + lr) * LDSS + ks + lk];
            #pragma unroll
            for (int mi = 0; mi < 4; mi++)
                #pragma unroll
                for (int ni = 0; ni < 4; ni++)
                    acc[mi][ni] = __builtin_amdgcn_mfma_f32_16x16x32_bf16(
                        av[mi], bv[ni], acc[mi][ni], 0, 0, 0);
        }
        __syncthreads();
    }
    const int rb = (lane >> 4) * 4;
    #pragma unroll
    for (int mi = 0; mi < 4; mi++) {
        #pragma unroll
        for (int ni = 0; ni < 4; ni++) {
            #pragma unroll
            for (int r = 0; r < 4; r++) {
                int ll = wm + mi * 16 + rb + r;
                int e = wn + ni * 16 + lr;
                float attn = acc[mi][ni][r] * zl[ll];
                float g = bf2f(gate[qbase + (size_t)(l0 + ll) * D_ + e]);
                y[qbase + (size_t)(l0 + ll) * D_ + e] = f2bf(attn * g);
            }
        }
    }
}

extern "C" void kernel_launch(void* const* d_in, const int* in_sizes, int n_in,
                              void* d_out, int out_size, void* d_ws, size_t ws_size,
                              hipStream_t stream)
{
    (void)in_sizes; (void)n_in; (void)out_size; (void)ws_size;
    const float* query = (const float*)d_in[0];
    const float* kv    = (const float*)d_in[1];
    const float* Wq    = (const float*)d_in[2];
    const float* Wg    = (const float*)d_in[3];
    const float* bg    = (const float*)d_in[4];
    const float* Wkv   = (const float*)d_in[5];
    const float* Wo    = (const float*)d_in[6];
    float* out = (float*)d_out;
    char* ws = (char*)d_ws;

    // workspace layout (bytes)
    unsigned short* q_feat    = (unsigned short*)(ws);                 // 64 MiB
    unsigned short* gate      = (unsigned short*)(ws + 67108864);      // 64 MiB
    unsigned short* kTb       = (unsigned short*)(ws + 134217728);     // 64 MiB [bh][d][s]
    unsigned short* vTb       = (unsigned short*)(ws + 201326592);     // 64 MiB [bh][d][s]
    float*          part      = (float*)(ws + 268435456);              // 32 MiB
    float*          ksum_part = (float*)(ws + 301989888);              // 256 KiB
    float*          ksum      = (float*)(ws + 302252032);              // 32 KiB
    unsigned short* kvsT      = (unsigned short*)(ws + 302284800);     // 2 MiB [bh][e][d]
    unsigned short* ybuf      = kTb;  // kT dead after kvsum_part; reuse for y

    dim3 blk(256, 1, 1);
    // q_feat + gate
    gemm_bt<0><<<dim3(128, 32), blk, 0, stream>>>(query, nullptr, Wq, Wg,
                                                  q_feat, gate, nullptr, bg);
    // k_feat^T, v^T
    gemm_bt<1><<<dim3(128, 32), blk, 0, stream>>>(kv, nullptr, Wkv, nullptr,
                                                  kTb, vTb, nullptr, nullptr);
    // kv_summary partials + ksum partials
    kvsum_part<<<dim3(8, 64), blk, 0, stream>>>(kTb, vTb, part, ksum_part);
    kvs_reduce<<<dim3(4096), blk, 0, stream>>>(part, kvsT, ksum_part, ksum);
    // attn * z * gate -> y
    attn_kernel<<<dim3(32, 16, 4), blk, 0, stream>>>(q_feat, kvsT, ksum, gate, ybuf);
    // out = y @ Wo^T
    gemm_bt<2><<<dim3(128, 16), blk, 0, stream>>>(nullptr, ybuf, Wo, nullptr,
                                                  nullptr, nullptr, out, nullptr);
}

// Round 3
// 1586.496 us; speedup vs baseline: 1.0105x; 1.0105x over previous
//
#include <hip/hip_runtime.h>

typedef __attribute__((ext_vector_type(8))) short bf16x8;
typedef __attribute__((ext_vector_type(4))) float f32x4;
typedef __attribute__((ext_vector_type(4))) unsigned int u32x4;

constexpr int B_ = 4, L_ = 4096, S_ = 4096, D_ = 2048, H_ = 16, HD_ = 128;
constexpr int BM = 128, BN = 128, BK = 64, LDSS = BK + 8; // 72

__device__ __forceinline__ unsigned short f2bf(float f) {
    unsigned int u = __builtin_bit_cast(unsigned int, f);
    return (unsigned short)((u + 0x7fffu + ((u >> 16) & 1u)) >> 16);
}
__device__ __forceinline__ float bf2f(unsigned short h) {
    unsigned int u = ((unsigned int)h) << 16;
    return __builtin_bit_cast(float, u);
}
__device__ __forceinline__ unsigned long long pack4(float a, float b, float c, float d) {
    return (unsigned long long)f2bf(a) | ((unsigned long long)f2bf(b) << 16)
         | ((unsigned long long)f2bf(c) << 32) | ((unsigned long long)f2bf(d) << 48);
}
__device__ __forceinline__ float featmap(float x) {
    return x > 0.f ? x + 1.f : __expf(x);
}

// C = A @ B^T with A [M,K] row-major, B [N,K] row-major (weights are [out,in]).
// MODE 0: A=query(f32). bn<16 -> C1=q_feat=featmap(.); bn>=16 -> B=Bw2(Wg), C2=gate=sigmoid(.+bias)
// MODE 1: A=kv(f32), B=Wkv[4096,2048]. bn<16 -> k: featmap, TRANSPOSED store to C1[bh][d][s];
//         bn>=16 -> v: passthrough, transposed store to C2.
// MODE 2: A=Ah(bf16)=y, B=Wo, plain fp32 output Cf.
template<int MODE>
__global__ __launch_bounds__(256) void gemm_bt(
    const float* __restrict__ Af, const unsigned short* __restrict__ Ah,
    const float* __restrict__ Bw, const float* __restrict__ Bw2,
    unsigned short* __restrict__ C1, unsigned short* __restrict__ C2,
    float* __restrict__ Cf, const float* __restrict__ bias)
{
    __shared__ unsigned short smem[BM * LDSS + BN * LDSS];
    unsigned short* As = smem;
    unsigned short* Bs = smem + BM * LDSS;
    const int tid = threadIdx.x;
    const int bm = blockIdx.x, bn = blockIdx.y;
    const int row0 = bm * BM;
    const int lane = tid & 63, w = tid >> 6;
    const int wm = (w >> 1) * 64, wn = (w & 1) * 64;
    const int lr = lane & 15, lk = (lane >> 4) * 8;
    const bool second = bn >= H_;
    const float* Bp = (MODE == 0 && second) ? Bw2 : Bw;
    const int bcol = (MODE == 0 && second) ? (bn - H_) * BN : bn * BN;

    f32x4 acc[4][4] = {};

    for (int k0 = 0; k0 < D_; k0 += BK) {
        if (MODE == 2) {
            #pragma unroll
            for (int i = 0; i < 4; i++) {
                int idx = tid + i * 256;
                int r = idx >> 3, c = (idx & 7) * 8;
                *(u32x4*)&As[r * LDSS + c] =
                    *(const u32x4*)&Ah[(size_t)(row0 + r) * D_ + k0 + c];
            }
        } else {
            #pragma unroll
            for (int i = 0; i < 8; i++) {
                int idx = tid + i * 256;
                int r = idx >> 4, c = (idx & 15) * 4;
                const float4 v = *(const float4*)&Af[(size_t)(row0 + r) * D_ + k0 + c];
                *(unsigned long long*)&As[r * LDSS + c] = pack4(v.x, v.y, v.z, v.w);
            }
        }
        #pragma unroll
        for (int i = 0; i < 8; i++) {
            int idx = tid + i * 256;
            int r = idx >> 4, c = (idx & 15) * 4;
            const float4 v = *(const float4*)&Bp[(size_t)(bcol + r) * D_ + k0 + c];
            *(unsigned long long*)&Bs[r * LDSS + c] = pack4(v.x, v.y, v.z, v.w);
        }
        __syncthreads();
        #pragma unroll
        for (int ks = 0; ks < BK; ks += 32) {
            bf16x8 av[4], bv[4];
            #pragma unroll
            for (int mi = 0; mi < 4; mi++)
                av[mi] = *(const bf16x8*)&As[(wm + mi * 16 + lr) * LDSS + ks + lk];
            #pragma unroll
            for (int ni = 0; ni < 4; ni++)
                bv[ni] = *(const bf16x8*)&Bs[(wn + ni * 16 + lr) * LDSS + ks + lk];
            #pragma unroll
            for (int mi = 0; mi < 4; mi++)
                #pragma unroll
                for (int ni = 0; ni < 4; ni++)
                    acc[mi][ni] = __builtin_amdgcn_mfma_f32_16x16x32_bf16(
                        av[mi], bv[ni], acc[mi][ni], 0, 0, 0);
        }
        __syncthreads();
    }

    const int rb = (lane >> 4) * 4;
    if (MODE == 1) {
        // transpose 128x128 tile through LDS, write [bh][d][s] coalesced
        unsigned short* TT = smem;          // 128*136 = 17408 <= 18432 (reuse As+Bs)
        const int TP = HD_ + 8;             // 136
        const int isv = second ? 1 : 0;
        const int h2 = bn & (H_ - 1);
        #pragma unroll
        for (int mi = 0; mi < 4; mi++) {
            #pragma unroll
            for (int ni = 0; ni < 4; ni++) {
                float x0 = acc[mi][ni][0], x1 = acc[mi][ni][1];
                float x2 = acc[mi][ni][2], x3 = acc[mi][ni][3];
                if (!isv) {
                    x0 = featmap(x0); x1 = featmap(x1);
                    x2 = featmap(x2); x3 = featmap(x3);
                }
                *(unsigned long long*)&TT[(wn + ni * 16 + lr) * TP + wm + mi * 16 + rb]
                    = pack4(x0, x1, x2, x3);
            }
        }
        __syncthreads();
        const int b = row0 >> 12;           // 4096 rows per batch
        const int sl0 = row0 & (S_ - 1);
        unsigned short* dst = (isv ? C2 : C1) + (size_t)(b * H_ + h2) * HD_ * S_;
        #pragma unroll
        for (int i = 0; i < 8; i++) {
            int idx = tid + 256 * i;
            int d = idx >> 4, sc = (idx & 15) * 8;
            *(u32x4*)&dst[(size_t)d * S_ + sl0 + sc] = *(const u32x4*)&TT[d * TP + sc];
        }
        return;
    }
    #pragma unroll
    for (int mi = 0; mi < 4; mi++) {
        #pragma unroll
        for (int ni = 0; ni < 4; ni++) {
            #pragma unroll
            for (int r = 0; r < 4; r++) {
                const size_t gr = (size_t)(row0 + wm + mi * 16 + rb + r);
                const int gc = bcol + wn + ni * 16 + lr;
                float x = acc[mi][ni][r];
                if (MODE == 0) {
                    if (!second) {
                        C1[gr * D_ + gc] = f2bf(featmap(x));
                    } else {
                        float t = x + bias[gc];
                        C2[gr * D_ + gc] = f2bf(1.f / (1.f + __expf(-t)));
                    }
                } else {
                    Cf[gr * D_ + gc] = x;
                }
            }
        }
    }
}

// kv_summary partials: per (s-chunk cx, bh): part[cx][bh][d][e] = sum_{s in chunk} k[s,d]*v[s,e]
// inputs are transposed [bh][d][s] so LDS staging is fully vectorized.
__global__ __launch_bounds__(256) void kvsum_part(
    const unsigned short* __restrict__ kT, const unsigned short* __restrict__ vT,
    float* __restrict__ part, float* __restrict__ ksum_part)
{
    __shared__ unsigned short kA[HD_ * LDSS];
    __shared__ unsigned short vB[HD_ * LDSS];
    __shared__ float red[HD_ * 8];
    const int tid = threadIdx.x;
    const int cx = blockIdx.x, bh = blockIdx.y;
    const int lane = tid & 63, w = tid >> 6;
    const int wm = (w >> 1) * 64, wn = (w & 1) * 64;
    const int lr = lane & 15, lk = (lane >> 4) * 8;
    const unsigned short* kb = kT + (size_t)bh * HD_ * S_;
    const unsigned short* vb = vT + (size_t)bh * HD_ * S_;
    f32x4 acc[4][4] = {};
    float ksl[4] = {0.f, 0.f, 0.f, 0.f};
    const int chunk = S_ / 8;
    const int s_begin = cx * chunk;
    for (int s0 = s_begin; s0 < s_begin + chunk; s0 += 64) {
        #pragma unroll
        for (int i = 0; i < 4; i++) {
            int idx = tid + i * 256;
            int d = idx >> 3, sc = (idx & 7) * 8;
            u32x4 kk = *(const u32x4*)&kb[(size_t)d * S_ + s0 + sc];
            *(u32x4*)&kA[d * LDSS + sc] = kk;
            unsigned short t8[8];
            *(u32x4*)t8 = kk;
            float ss = 0.f;
            #pragma unroll
            for (int j = 0; j < 8; j++) ss += bf2f(t8[j]);
            ksl[i] += ss;
            *(u32x4*)&vB[d * LDSS + sc] = *(const u32x4*)&vb[(size_t)d * S_ + s0 + sc];
        }
        __syncthreads();
        #pragma unroll
        for (int ks = 0; ks < 64; ks += 32) {
            bf16x8 av[4], bv[4];
            #pragma unroll
            for (int mi = 0; mi < 4; mi++)
                av[mi] = *(const bf16x8*)&kA[(wm + mi * 16 + lr) * LDSS + ks + lk];
            #pragma unroll
            for (int ni = 0; ni < 4; ni++)
                bv[ni] = *(const bf16x8*)&vB[(wn + ni * 16 + lr) * LDSS + ks + lk];
            #pragma unroll
            for (int mi = 0; mi < 4; mi++)
                #pragma unroll
                for (int ni = 0; ni < 4; ni++)
                    acc[mi][ni] = __builtin_amdgcn_mfma_f32_16x16x32_bf16(
                        av[mi], bv[ni], acc[mi][ni], 0, 0, 0);
        }
        __syncthreads();
    }
    // k_sum partial: thread covered d = tid>>3 + 32*i, 8 s-values per stage
    #pragma unroll
    for (int i = 0; i < 4; i++) red[((tid >> 3) + 32 * i) * 8 + (tid & 7)] = ksl[i];
    __syncthreads();
    if (tid < HD_) {
        float s = 0.f;
        #pragma unroll
        for (int j = 0; j < 8; j++) s += red[tid * 8 + j];
        ksum_part[(size_t)cx * (64 * HD_) + bh * HD_ + tid] = s;
    }
    const int rb = (lane >> 4) * 4;
    float* pp = part + ((size_t)cx * 64 + bh) * (HD_ * HD_);
    #pragma unroll
    for (int mi = 0; mi < 4; mi++)
        #pragma unroll
        for (int ni = 0; ni < 4; ni++)
            #pragma unroll
            for (int r = 0; r < 4; r++)
                pp[(wm + mi * 16 + rb + r) * HD_ + wn + ni * 16 + lr] = acc[mi][ni][r];
}

// reduce 8 partials -> kvsT[bh][e][d] (bf16, transposed so attn B-frags are contiguous) + ksum
__global__ __launch_bounds__(256) void kvs_reduce(
    const float* __restrict__ part, unsigned short* __restrict__ kvsT,
    const float* __restrict__ ksum_part, float* __restrict__ ksum)
{
    const int idx = blockIdx.x * 256 + threadIdx.x;
    const int e = idx & 127, d2 = (idx >> 7) & 127, bh = idx >> 14;
    float s = 0.f;
    #pragma unroll
    for (int cx = 0; cx < 8; cx++)
        s += part[((size_t)cx * 64 + bh) * 16384 + d2 * 128 + e];
    kvsT[((size_t)bh * 128 + e) * 128 + d2] = f2bf(s);
    if (idx < 64 * 128) {
        float t = 0.f;
        #pragma unroll
        for (int cx = 0; cx < 8; cx++) t += ksum_part[cx * 8192 + idx];
        ksum[idx] = t;
    }
}

// attn = (q @ kvs) * z * gate -> y (bf16)
__global__ __launch_bounds__(256) void attn_kernel(
    const unsigned short* __restrict__ qf, const unsigned short* __restrict__ kvsT,
    const float* __restrict__ ksum, const unsigned short* __restrict__ gate,
    unsigned short* __restrict__ y)
{
    __shared__ unsigned short qs[128 * 136];
    __shared__ unsigned short bs[128 * LDSS];
    __shared__ float zl[128];
    const int tid = threadIdx.x;
    const int l0 = blockIdx.x * 128;
    const int h = blockIdx.y, b = blockIdx.z;
    const int bh = b * H_ + h;
    const int lane = tid & 63, w = tid >> 6;
    const int wm = (w >> 1) * 64, wn = (w & 1) * 64;
    const int lr = lane & 15, lk = (lane >> 4) * 8;
    const size_t qbase = (size_t)b * L_ * D_ + (size_t)h * HD_;
    #pragma unroll
    for (int i = 0; i < 8; i++) {
        int idx = tid + i * 256;
        int r = idx >> 4, c = (idx & 15) * 8;
        *(u32x4*)&qs[r * 136 + c] = *(const u32x4*)&qf[qbase + (size_t)(l0 + r) * D_ + c];
    }
    __syncthreads();
    if (tid < 128) {
        const float* kp = ksum + bh * HD_;
        float sden = 0.f;
        #pragma unroll 4
        for (int d2 = 0; d2 < HD_; d2++) sden += bf2f(qs[tid * 136 + d2]) * kp[d2];
        zl[tid] = 1.f / (sden + 1e-6f);
    }
    f32x4 acc[4][4] = {};
    for (int kc = 0; kc < 2; kc++) {
        #pragma unroll
        for (int i = 0; i < 4; i++) {
            int idx = tid + i * 256;
            int e = idx >> 3, dc = (idx & 7) * 8;
            *(u32x4*)&bs[e * LDSS + dc] =
                *(const u32x4*)&kvsT[((size_t)bh * 128 + e) * 128 + kc * 64 + dc];
        }
        __syncthreads();
        #pragma unroll
        for (int ks = 0; ks < 64; ks += 32) {
            bf16x8 av[4], bv[4];
            #pragma unroll
            for (int mi = 0; mi < 4; mi++)
                av[mi] = *(const bf16x8*)&qs[(wm + mi * 16 + lr) * 136 + kc * 64 + ks + lk];
            #pragma unroll
            for (int ni = 0; ni < 4; ni++)
                bv[ni] = *(const bf16x8*)&bs[(wn + ni * 16 + lr) * LDSS + ks + lk];
            #pragma unroll
            for (int mi = 0; mi < 4; mi++)
                #pragma unroll
                for (int ni = 0; ni < 4; ni++)
                    acc[mi][ni] = __builtin_amdgcn_mfma_f32_16x16x32_bf16(
                        av[mi], bv[ni], acc[mi][ni], 0, 0, 0);
        }
        __syncthreads();
    }
    const int rb = (lane >> 4) * 4;
    #pragma unroll
    for (int mi = 0; mi < 4; mi++) {
        #pragma unroll
        for (int ni = 0; ni < 4; ni++) {
            #pragma unroll
            for (int r = 0; r < 4; r++) {
                int ll = wm + mi * 16 + rb + r;
                int e = wn + ni * 16 + lr;
                float attn = acc[mi][ni][r] * zl[ll];
                float g = bf2f(gate[qbase + (size_t)(l0 + ll) * D_ + e]);
                y[qbase + (size_t)(l0 + ll) * D_ + e] = f2bf(attn * g);
            }
        }
    }
}

extern "C" void kernel_launch(void* const* d_in, const int* in_sizes, int n_in,
                              void* d_out, int out_size, void* d_ws, size_t ws_size,
                              hipStream_t stream)
{
    (void)in_sizes; (void)n_in; (void)out_size; (void)ws_size;
    const float* query = (const float*)d_in[0];
    const float* kv    = (const float*)d_in[1];
    const float* Wq    = (const float*)d_in[2];
    const float* Wg    = (const float*)d_in[3];
    const float* bg    = (const float*)d_in[4];
    const float* Wkv   = (const float*)d_in[5];
    const float* Wo    = (const float*)d_in[6];
    float* out = (float*)d_out;
    char* ws = (char*)d_ws;

    // workspace layout (bytes)
    unsigned short* q_feat    = (unsigned short*)(ws);                 // 64 MiB
    unsigned short* gate      = (unsigned short*)(ws + 67108864);      // 64 MiB
    unsigned short* kTb       = (unsigned short*)(ws + 134217728);     // 64 MiB [bh][d][s]
    unsigned short* vTb       = (unsigned short*)(ws + 201326592);     // 64 MiB [bh][d][s]
    float*          part      = (float*)(ws + 268435456);              // 32 MiB
    float*          ksum_part = (float*)(ws + 301989888);              // 256 KiB
    float*          ksum      = (float*)(ws + 302252032);              // 32 KiB
    unsigned short* kvsT      = (unsigned short*)(ws + 302284800);     // 2 MiB [bh][e][d]
    unsigned short* ybuf      = kTb;  // kT dead after kvsum_part; reuse for y

    dim3 blk(256, 1, 1);
    // q_feat + gate
    gemm_bt<0><<<dim3(128, 32), blk, 0, stream>>>(query, nullptr, Wq, Wg,
                                                  q_feat, gate, nullptr, bg);
    // k_feat^T, v^T
    gemm_bt<1><<<dim3(128, 32), blk, 0, stream>>>(kv, nullptr, Wkv, nullptr,
                                                  kTb, vTb, nullptr, nullptr);
    // kv_summary partials + ksum partials
    kvsum_part<<<dim3(8, 64), blk, 0, stream>>>(kTb, vTb, part, ksum_part);
    kvs_reduce<<<dim3(4096), blk, 0, stream>>>(part, kvsT, ksum_part, ksum);
    // attn * z * gate -> y
    attn_kernel<<<dim3(32, 16, 4), blk, 0, stream>>>(q_feat, kvsT, ksum, gate, ybuf);
    // out = y @ Wo^T
    gemm_bt<2><<<dim3(128, 16), blk, 0, stream>>>(nullptr, ybuf, Wo, nullptr,
                                                  nullptr, nullptr, out, nullptr);
}

// Round 4
// 1260.549 us; speedup vs baseline: 1.2718x; 1.2586x over previous
//
#include <hip/hip_runtime.h>

typedef __attribute__((ext_vector_type(8))) short bf16x8;
typedef __attribute__((ext_vector_type(4))) float f32x4;
typedef __attribute__((ext_vector_type(4))) unsigned int u32x4;

constexpr int L_ = 4096, S_ = 4096, D_ = 2048, H_ = 16, HD_ = 128;
constexpr int LDSS = 72; // padded stride for the small (non-gload) kernels

__device__ __forceinline__ unsigned short f2bf(float f) {
    unsigned int u = __builtin_bit_cast(unsigned int, f);
    return (unsigned short)((u + 0x7fffu + ((u >> 16) & 1u)) >> 16);
}
__device__ __forceinline__ float bf2f(unsigned short h) {
    unsigned int u = ((unsigned int)h) << 16;
    return __builtin_bit_cast(float, u);
}
__device__ __forceinline__ unsigned long long pack4(float a, float b, float c, float d) {
    return (unsigned long long)f2bf(a) | ((unsigned long long)f2bf(b) << 16)
         | ((unsigned long long)f2bf(c) << 32) | ((unsigned long long)f2bf(d) << 48);
}
__device__ __forceinline__ float featmap(float x) {
    return x > 0.f ? x + 1.f : __expf(x);
}
__device__ __forceinline__ void gload16(const unsigned short* g, unsigned short* l) {
    __builtin_amdgcn_global_load_lds(
        (const __attribute__((address_space(1))) void*)g,
        (__attribute__((address_space(3))) void*)l, 16, 0, 0);
}

// fp32 -> bf16 bulk convert, 8 elems/thread/iter (2x float4 in, 16B out)
__global__ __launch_bounds__(256) void cvt_bf16(
    const float* __restrict__ in, unsigned short* __restrict__ out, int n8)
{
    const int stride = gridDim.x * 256;
    for (int i = blockIdx.x * 256 + threadIdx.x; i < n8; i += stride) {
        const float4 a = ((const float4*)in)[2 * i];
        const float4 b = ((const float4*)in)[2 * i + 1];
        unsigned long long* o = (unsigned long long*)&out[(size_t)i * 8];
        o[0] = pack4(a.x, a.y, a.z, a.w);
        o[1] = pack4(b.x, b.y, b.z, b.w);
    }
}

// C = A @ B^T, A bf16 [M][2048] row-major, B bf16 [Ncols][2048] row-major.
// m97 structure: 128x128 tile, BK=64, 4 waves, global_load_lds(16) -> linear LDS.
// MODE 0: bn<16 -> C1=featmap(.) [q_feat]; bn>=16 -> C2=sigmoid(.+bias) [gate]
// MODE 1: bn<16 -> featmap, transposed store C1[bh][d][s] (kT); bn>=16 -> transposed C2 (vT)
// MODE 2: Cf = fp32 result (final output)
template<int MODE>
__global__ __launch_bounds__(256) void gemm_lds(
    const unsigned short* __restrict__ A, const unsigned short* __restrict__ B,
    unsigned short* __restrict__ C1, unsigned short* __restrict__ C2,
    float* __restrict__ Cf, const float* __restrict__ bias)
{
    __shared__ unsigned short smem[17408];      // As 128x64 | Bs 128x64 (32KB) ; TT 128x136 reuse
    unsigned short* As = smem;
    unsigned short* Bs = smem + 8192;
    const int tid = threadIdx.x;
    const int bm = blockIdx.x, bn = blockIdx.y;
    const int row0 = bm * 128, bcol = bn * 128;
    const int lane = tid & 63, w = tid >> 6;
    const int wm = (w >> 1) * 64, wn = (w & 1) * 64;
    const int lr = lane & 15, lk = (lane >> 4) * 8;
    const int sr = tid >> 3;                    // staging row within 32-row group
    const int sc = (tid & 7) * 8;               // staging col (shorts)
    const int wbase = (tid & 192) * 8;          // wave-uniform LDS short offset (w*512)
    const unsigned short* Ap = A + (size_t)row0 * D_;
    const unsigned short* Bp = B + (size_t)bcol * D_;

    f32x4 acc[4][4] = {};

    for (int k0 = 0; k0 < D_; k0 += 64) {
        #pragma unroll
        for (int i = 0; i < 4; i++)
            gload16(&Ap[(size_t)(i * 32 + sr) * D_ + k0 + sc], &As[i * 2048 + wbase]);
        #pragma unroll
        for (int i = 0; i < 4; i++)
            gload16(&Bp[(size_t)(i * 32 + sr) * D_ + k0 + sc], &Bs[i * 2048 + wbase]);
        __syncthreads();
        #pragma unroll
        for (int ks = 0; ks < 64; ks += 32) {
            bf16x8 av[4], bv[4];
            #pragma unroll
            for (int mi = 0; mi < 4; mi++)
                av[mi] = *(const bf16x8*)&As[(wm + mi * 16 + lr) * 64 + ks + lk];
            #pragma unroll
            for (int ni = 0; ni < 4; ni++)
                bv[ni] = *(const bf16x8*)&Bs[(wn + ni * 16 + lr) * 64 + ks + lk];
            #pragma unroll
            for (int mi = 0; mi < 4; mi++)
                #pragma unroll
                for (int ni = 0; ni < 4; ni++)
                    acc[mi][ni] = __builtin_amdgcn_mfma_f32_16x16x32_bf16(
                        av[mi], bv[ni], acc[mi][ni], 0, 0, 0);
        }
        __syncthreads();
    }

    const int rb = (lane >> 4) * 4;
    const bool second = bn >= H_;
    if (MODE == 1) {
        unsigned short* TT = smem;              // 128*136 = 17408 shorts
        const int TP = HD_ + 8;
        const int h2 = bn & (H_ - 1);
        #pragma unroll
        for (int mi = 0; mi < 4; mi++) {
            #pragma unroll
            for (int ni = 0; ni < 4; ni++) {
                float x0 = acc[mi][ni][0], x1 = acc[mi][ni][1];
                float x2 = acc[mi][ni][2], x3 = acc[mi][ni][3];
                if (!second) {
                    x0 = featmap(x0); x1 = featmap(x1);
                    x2 = featmap(x2); x3 = featmap(x3);
                }
                *(unsigned long long*)&TT[(wn + ni * 16 + lr) * TP + wm + mi * 16 + rb]
                    = pack4(x0, x1, x2, x3);
            }
        }
        __syncthreads();
        const int b = row0 >> 12;
        const int sl0 = row0 & (S_ - 1);
        unsigned short* dst = (second ? C2 : C1) + (size_t)(b * H_ + h2) * HD_ * S_;
        #pragma unroll
        for (int i = 0; i < 8; i++) {
            int idx = tid + 256 * i;
            int d = idx >> 4, sc2 = (idx & 15) * 8;
            *(u32x4*)&dst[(size_t)d * S_ + sl0 + sc2] = *(const u32x4*)&TT[d * TP + sc2];
        }
        return;
    }
    #pragma unroll
    for (int mi = 0; mi < 4; mi++) {
        #pragma unroll
        for (int ni = 0; ni < 4; ni++) {
            #pragma unroll
            for (int r = 0; r < 4; r++) {
                const size_t gr = (size_t)(row0 + wm + mi * 16 + rb + r);
                const int gc = bcol + wn + ni * 16 + lr;
                float x = acc[mi][ni][r];
                if (MODE == 0) {
                    if (!second) {
                        C1[gr * D_ + gc] = f2bf(featmap(x));
                    } else {
                        const int gc2 = gc - D_;
                        float t = x + bias[gc2];
                        C2[gr * D_ + gc2] = f2bf(1.f / (1.f + __expf(-t)));
                    }
                } else {
                    Cf[gr * D_ + gc] = x;
                }
            }
        }
    }
}

// kv_summary partials: per (s-chunk cx, bh): part[cx][bh][d][e] = sum_s k[s,d]*v[s,e]
__global__ __launch_bounds__(256) void kvsum_part(
    const unsigned short* __restrict__ kT, const unsigned short* __restrict__ vT,
    float* __restrict__ part, float* __restrict__ ksum_part)
{
    __shared__ unsigned short kA[HD_ * LDSS];
    __shared__ unsigned short vB[HD_ * LDSS];
    __shared__ float red[HD_ * 8];
    const int tid = threadIdx.x;
    const int cx = blockIdx.x, bh = blockIdx.y;
    const int lane = tid & 63, w = tid >> 6;
    const int wm = (w >> 1) * 64, wn = (w & 1) * 64;
    const int lr = lane & 15, lk = (lane >> 4) * 8;
    const unsigned short* kb = kT + (size_t)bh * HD_ * S_;
    const unsigned short* vb = vT + (size_t)bh * HD_ * S_;
    f32x4 acc[4][4] = {};
    float ksl[4] = {0.f, 0.f, 0.f, 0.f};
    const int chunk = S_ / 8;
    const int s_begin = cx * chunk;
    for (int s0 = s_begin; s0 < s_begin + chunk; s0 += 64) {
        #pragma unroll
        for (int i = 0; i < 4; i++) {
            int idx = tid + i * 256;
            int d = idx >> 3, sc = (idx & 7) * 8;
            u32x4 kk = *(const u32x4*)&kb[(size_t)d * S_ + s0 + sc];
            *(u32x4*)&kA[d * LDSS + sc] = kk;
            unsigned short t8[8];
            *(u32x4*)t8 = kk;
            float ss = 0.f;
            #pragma unroll
            for (int j = 0; j < 8; j++) ss += bf2f(t8[j]);
            ksl[i] += ss;
            *(u32x4*)&vB[d * LDSS + sc] = *(const u32x4*)&vb[(size_t)d * S_ + s0 + sc];
        }
        __syncthreads();
        #pragma unroll
        for (int ks = 0; ks < 64; ks += 32) {
            bf16x8 av[4], bv[4];
            #pragma unroll
            for (int mi = 0; mi < 4; mi++)
                av[mi] = *(const bf16x8*)&kA[(wm + mi * 16 + lr) * LDSS + ks + lk];
            #pragma unroll
            for (int ni = 0; ni < 4; ni++)
                bv[ni] = *(const bf16x8*)&vB[(wn + ni * 16 + lr) * LDSS + ks + lk];
            #pragma unroll
            for (int mi = 0; mi < 4; mi++)
                #pragma unroll
                for (int ni = 0; ni < 4; ni++)
                    acc[mi][ni] = __builtin_amdgcn_mfma_f32_16x16x32_bf16(
                        av[mi], bv[ni], acc[mi][ni], 0, 0, 0);
        }
        __syncthreads();
    }
    #pragma unroll
    for (int i = 0; i < 4; i++) red[((tid >> 3) + 32 * i) * 8 + (tid & 7)] = ksl[i];
    __syncthreads();
    if (tid < HD_) {
        float s = 0.f;
        #pragma unroll
        for (int j = 0; j < 8; j++) s += red[tid * 8 + j];
        ksum_part[(size_t)cx * (64 * HD_) + bh * HD_ + tid] = s;
    }
    const int rb = (lane >> 4) * 4;
    float* pp = part + ((size_t)cx * 64 + bh) * (HD_ * HD_);
    #pragma unroll
    for (int mi = 0; mi < 4; mi++)
        #pragma unroll
        for (int ni = 0; ni < 4; ni++)
            #pragma unroll
            for (int r = 0; r < 4; r++)
                pp[(wm + mi * 16 + rb + r) * HD_ + wn + ni * 16 + lr] = acc[mi][ni][r];
}

__global__ __launch_bounds__(256) void kvs_reduce(
    const float* __restrict__ part, unsigned short* __restrict__ kvsT,
    const float* __restrict__ ksum_part, float* __restrict__ ksum)
{
    const int idx = blockIdx.x * 256 + threadIdx.x;
    const int e = idx & 127, d2 = (idx >> 7) & 127, bh = idx >> 14;
    float s = 0.f;
    #pragma unroll
    for (int cx = 0; cx < 8; cx++)
        s += part[((size_t)cx * 64 + bh) * 16384 + d2 * 128 + e];
    kvsT[((size_t)bh * 128 + e) * 128 + d2] = f2bf(s);
    if (idx < 64 * 128) {
        float t = 0.f;
        #pragma unroll
        for (int cx = 0; cx < 8; cx++) t += ksum_part[cx * 8192 + idx];
        ksum[idx] = t;
    }
}

// attn = (q @ kvs) * z * gate -> y (bf16)
__global__ __launch_bounds__(256) void attn_kernel(
    const unsigned short* __restrict__ qf, const unsigned short* __restrict__ kvsT,
    const float* __restrict__ ksum, const unsigned short* __restrict__ gate,
    unsigned short* __restrict__ y)
{
    __shared__ unsigned short qs[128 * 136];
    __shared__ unsigned short bs[128 * LDSS];
    __shared__ float zl[128];
    const int tid = threadIdx.x;
    const int l0 = blockIdx.x * 128;
    const int h = blockIdx.y, b = blockIdx.z;
    const int bh = b * H_ + h;
    const int lane = tid & 63, w = tid >> 6;
    const int wm = (w >> 1) * 64, wn = (w & 1) * 64;
    const int lr = lane & 15, lk = (lane >> 4) * 8;
    const size_t qbase = (size_t)b * L_ * D_ + (size_t)h * HD_;
    #pragma unroll
    for (int i = 0; i < 8; i++) {
        int idx = tid + i * 256;
        int r = idx >> 4, c = (idx & 15) * 8;
        *(u32x4*)&qs[r * 136 + c] = *(const u32x4*)&qf[qbase + (size_t)(l0 + r) * D_ + c];
    }
    __syncthreads();
    if (tid < 128) {
        const float* kp = ksum + bh * HD_;
        float sden = 0.f;
        #pragma unroll 4
        for (int d2 = 0; d2 < HD_; d2++) sden += bf2f(qs[tid * 136 + d2]) * kp[d2];
        zl[tid] = 1.f / (sden + 1e-6f);
    }
    f32x4 acc[4][4] = {};
    for (int kc = 0; kc < 2; kc++) {
        #pragma unroll
        for (int i = 0; i < 4; i++) {
            int idx = tid + i * 256;
            int e = idx >> 3, dc = (idx & 7) * 8;
            *(u32x4*)&bs[e * LDSS + dc] =
                *(const u32x4*)&kvsT[((size_t)bh * 128 + e) * 128 + kc * 64 + dc];
        }
        __syncthreads();
        #pragma unroll
        for (int ks = 0; ks < 64; ks += 32) {
            bf16x8 av[4], bv[4];
            #pragma unroll
            for (int mi = 0; mi < 4; mi++)
                av[mi] = *(const bf16x8*)&qs[(wm + mi * 16 + lr) * 136 + kc * 64 + ks + lk];
            #pragma unroll
            for (int ni = 0; ni < 4; ni++)
                bv[ni] = *(const bf16x8*)&bs[(wn + ni * 16 + lr) * LDSS + ks + lk];
            #pragma unroll
            for (int mi = 0; mi < 4; mi++)
                #pragma unroll
                for (int ni = 0; ni < 4; ni++)
                    acc[mi][ni] = __builtin_amdgcn_mfma_f32_16x16x32_bf16(
                        av[mi], bv[ni], acc[mi][ni], 0, 0, 0);
        }
        __syncthreads();
    }
    const int rb = (lane >> 4) * 4;
    #pragma unroll
    for (int mi = 0; mi < 4; mi++) {
        #pragma unroll
        for (int ni = 0; ni < 4; ni++) {
            #pragma unroll
            for (int r = 0; r < 4; r++) {
                int ll = wm + mi * 16 + rb + r;
                int e = wn + ni * 16 + lr;
                float attn = acc[mi][ni][r] * zl[ll];
                float g = bf2f(gate[qbase + (size_t)(l0 + ll) * D_ + e]);
                y[qbase + (size_t)(l0 + ll) * D_ + e] = f2bf(attn * g);
            }
        }
    }
}

extern "C" void kernel_launch(void* const* d_in, const int* in_sizes, int n_in,
                              void* d_out, int out_size, void* d_ws, size_t ws_size,
                              hipStream_t stream)
{
    (void)in_sizes; (void)n_in; (void)out_size; (void)ws_size;
    const float* query = (const float*)d_in[0];
    const float* kv    = (const float*)d_in[1];
    const float* Wq    = (const float*)d_in[2];
    const float* Wg    = (const float*)d_in[3];
    const float* bg    = (const float*)d_in[4];
    const float* Wkv   = (const float*)d_in[5];
    const float* Wo    = (const float*)d_in[6];
    float* out = (float*)d_out;
    char* ws = (char*)d_ws;

    // workspace layout (bytes). Region R is time-shared (stream-ordered):
    //   phase1: qbf(64Mi)+Wqg(16Mi) ; phase2: kvbf(64Mi)+Wkvb(16Mi)
    //   phase3: part(32Mi)+ksum_part+ksum+kvsT. Wob lives at R+80Mi.
    unsigned short* q_feat = (unsigned short*)(ws);                 // 64 MiB
    unsigned short* gate   = (unsigned short*)(ws + 67108864);      // 64 MiB
    unsigned short* kTb    = (unsigned short*)(ws + 134217728);     // 64 MiB [bh][d][s]
    unsigned short* vTb    = (unsigned short*)(ws + 201326592);     // 64 MiB [bh][d][s]
    char* R = ws + 268435456;
    unsigned short* qbf    = (unsigned short*)(R);                  // 64 MiB (phase1)
    unsigned short* Wqg    = (unsigned short*)(R + 67108864);       // 16 MiB (phase1)
    unsigned short* kvbf   = (unsigned short*)(R);                  // 64 MiB (phase2)
    unsigned short* Wkvb   = (unsigned short*)(R + 67108864);       // 16 MiB (phase2)
    float* part            = (float*)(R);                           // 32 MiB (phase3)
    float* ksum_part       = (float*)(R + 33554432);                // 256 KiB
    float* ksum            = (float*)(R + 33816576);                // 32 KiB
    unsigned short* kvsT   = (unsigned short*)(R + 33849344);       // 2 MiB [bh][e][d]
    unsigned short* Wob    = (unsigned short*)(R + 83886080);       // 8 MiB
    unsigned short* ybuf   = kTb;   // kT dead after kvsum_part

    dim3 blk(256, 1, 1);
    // ---- phase 1: q path ----
    cvt_bf16<<<dim3(2048), blk, 0, stream>>>(query, qbf, 4194304);
    cvt_bf16<<<dim3(2048), blk, 0, stream>>>(Wq, Wqg, 524288);
    cvt_bf16<<<dim3(2048), blk, 0, stream>>>(Wg, Wqg + 4194304, 524288);
    cvt_bf16<<<dim3(2048), blk, 0, stream>>>(Wo, Wob, 524288);
    gemm_lds<0><<<dim3(128, 32), blk, 0, stream>>>(qbf, Wqg, q_feat, gate, nullptr, bg);
    // ---- phase 2: kv path (reuses R after gemm<0> finished reading qbf/Wqg) ----
    cvt_bf16<<<dim3(2048), blk, 0, stream>>>(kv, kvbf, 4194304);
    cvt_bf16<<<dim3(2048), blk, 0, stream>>>(Wkv, Wkvb, 1048576);
    gemm_lds<1><<<dim3(128, 32), blk, 0, stream>>>(kvbf, Wkvb, kTb, vTb, nullptr, nullptr);
    // ---- phase 3: summary + attention ----
    kvsum_part<<<dim3(8, 64), blk, 0, stream>>>(kTb, vTb, part, ksum_part);
    kvs_reduce<<<dim3(4096), blk, 0, stream>>>(part, kvsT, ksum_part, ksum);
    attn_kernel<<<dim3(32, 16, 4), blk, 0, stream>>>(q_feat, kvsT, ksum, gate, ybuf);
    // ---- output projection ----
    gemm_lds<2><<<dim3(128, 16), blk, 0, stream>>>(ybuf, Wob, nullptr, nullptr, out, nullptr);
}

// Round 5
// 987.675 us; speedup vs baseline: 1.6232x; 1.2763x over previous
//
#include <hip/hip_runtime.h>

typedef __attribute__((ext_vector_type(8))) short bf16x8;
typedef __attribute__((ext_vector_type(4))) float f32x4;
typedef __attribute__((ext_vector_type(4))) unsigned int u32x4;

constexpr int L_ = 4096, S_ = 4096, D_ = 2048, H_ = 16, HD_ = 128;
constexpr int LDSS = 72; // padded stride for the small kernels

__device__ __forceinline__ unsigned short f2bf(float f) {
    unsigned int u = __builtin_bit_cast(unsigned int, f);
    return (unsigned short)((u + 0x7fffu + ((u >> 16) & 1u)) >> 16);
}
__device__ __forceinline__ float bf2f(unsigned short h) {
    unsigned int u = ((unsigned int)h) << 16;
    return __builtin_bit_cast(float, u);
}
__device__ __forceinline__ unsigned long long pack4(float a, float b, float c, float d) {
    return (unsigned long long)f2bf(a) | ((unsigned long long)f2bf(b) << 16)
         | ((unsigned long long)f2bf(c) << 32) | ((unsigned long long)f2bf(d) << 48);
}
__device__ __forceinline__ float featmap(float x) {
    return x > 0.f ? x + 1.f : __expf(x);
}
__device__ __forceinline__ void gload16(const unsigned short* g, unsigned short* l) {
    __builtin_amdgcn_global_load_lds(
        (const __attribute__((address_space(1))) void*)g,
        (__attribute__((address_space(3))) void*)l, 16, 0, 0);
}

// fp32 -> bf16 bulk convert
__global__ __launch_bounds__(256) void cvt_bf16(
    const float* __restrict__ in, unsigned short* __restrict__ out, int n8)
{
    const int stride = gridDim.x * 256;
    for (int i = blockIdx.x * 256 + threadIdx.x; i < n8; i += stride) {
        const float4 a = ((const float4*)in)[2 * i];
        const float4 b = ((const float4*)in)[2 * i + 1];
        unsigned long long* o = (unsigned long long*)&out[(size_t)i * 8];
        o[0] = pack4(a.x, a.y, a.z, a.w);
        o[1] = pack4(b.x, b.y, b.z, b.w);
    }
}

// ===================== 256x256 8-phase GEMM (T2+T3+T4+T5) =====================
// C = A @ B^T, A bf16 [M][2048], B bf16 [Ncols][2048]. K=2048, BK=64, 2 K-tiles/iter.
// 8 waves (2 wr x 4 wc), per-wave C = 128x64. LDS 128KiB: A[2buf][2half][128][64] | B same.
// A-half h = rows with bit6==h (m-quadrant); B-half h = rows with bit5==h (n-quadrant).
// Swizzle: LDS[lrow][col16] holds global[grow(lrow)][col16 ^ (lrow&7)] (both-sides XOR).
// MODE 0: bn<8 -> C1=featmap; bn>=8 -> C2=sigmoid(.+bias). MODE 1: transposed k/v store.
// MODE 2: Cf fp32.
template<int MODE, int NBN>
__global__ __launch_bounds__(512, 2) void gemm256(
    const unsigned short* __restrict__ A, const unsigned short* __restrict__ B,
    unsigned short* __restrict__ C1, unsigned short* __restrict__ C2,
    float* __restrict__ Cf, const float* __restrict__ bias)
{
    __shared__ alignas(16) unsigned short lds[65536];   // 128 KiB
    const int tid = threadIdx.x;
    const int lane = tid & 63, w = tid >> 6;
    const int wr = w >> 2, wc = w & 3;
    const int lr = lane & 15;
    const int lk8 = (lane >> 4) * 8;          // K-element offset within 32-group
    const int rsw = (lr & 7) << 3;            // read-side swizzle (shorts)
    const int lsub = lane >> 3;               // 0..7
    const int scol = ((lane & 7) ^ lsub) * 8; // pre-swizzled source col (elements)

    // bijective XCD swizzle (nwg % 8 == 0 for all our grids)
    const int nwg = gridDim.x;
    const int wg = blockIdx.x;
    const int swz = (wg & 7) * (nwg >> 3) + (wg >> 3);
    const int bm = swz / NBN, bn = swz % NBN;
    const int row0 = bm * 256, bcol = bn * 256;

    const unsigned short* Ap = A + (size_t)row0 * D_;
    const unsigned short* Bp = B + (size_t)bcol * D_;
    const int rA = w * 8 + lsub;                              // A stage row (r=0)
    const int rB = ((w * 8 + lsub) >> 5) * 64 + ((w * 8 + lsub) & 31); // B stage row base

    f32x4 acc[8][4] = {};
    bf16x8 av[2][4], bv[2][4];

#define STA(BUF, HH, KT) do { \
    const unsigned short* g_ = Ap + (size_t)((HH) * 64 + rA) * D_ + (KT) * 64 + scol; \
    unsigned short* l_ = &lds[(BUF) * 16384 + (HH) * 8192 + w * 512]; \
    gload16(g_, l_); gload16(g_ + (size_t)128 * D_, l_ + 4096); } while (0)

#define STB(BUF, HH, KT) do { \
    const unsigned short* g_ = Bp + (size_t)(rB + (HH) * 32) * D_ + (KT) * 64 + scol; \
    unsigned short* l_ = &lds[32768 + (BUF) * 16384 + (HH) * 8192 + w * 512]; \
    gload16(g_, l_); gload16(g_ + (size_t)128 * D_, l_ + 4096); } while (0)

#define RD_A(MQ, BUF) \
    _Pragma("unroll") for (int mi = 0; mi < 4; mi++) \
    _Pragma("unroll") for (int ks = 0; ks < 2; ks++) \
        av[ks][mi] = *(const bf16x8*)&lds[(BUF) * 16384 + (MQ) * 8192 \
            + (mi * 16 + lr + wr * 64) * 64 + ((ks * 32 + lk8) ^ rsw)];

#define RD_B(NQ, BUF) \
    _Pragma("unroll") for (int j = 0; j < 2; j++) \
    _Pragma("unroll") for (int ks = 0; ks < 2; ks++) \
        bv[ks][(NQ) * 2 + j] = *(const bf16x8*)&lds[32768 + (BUF) * 16384 + (NQ) * 8192 \
            + (j * 16 + lr + wc * 32) * 64 + ((ks * 32 + lk8) ^ rsw)];

#define MFMA_Q(MQ, NQ) \
    __builtin_amdgcn_s_setprio(1); \
    _Pragma("unroll") for (int mi = 0; mi < 4; mi++) \
    _Pragma("unroll") for (int j = 0; j < 2; j++) \
    _Pragma("unroll") for (int ks = 0; ks < 2; ks++) \
        acc[(MQ) * 4 + mi][(NQ) * 2 + j] = __builtin_amdgcn_mfma_f32_16x16x32_bf16( \
            av[ks][mi], bv[ks][(NQ) * 2 + j], acc[(MQ) * 4 + mi][(NQ) * 2 + j], 0, 0, 0); \
    __builtin_amdgcn_s_setprio(0);

#define BAR __builtin_amdgcn_s_barrier()
#define LGKM do { asm volatile("s_waitcnt lgkmcnt(0)" ::: "memory"); \
                  __builtin_amdgcn_sched_barrier(0); } while (0)
#define VM6 asm volatile("s_waitcnt vmcnt(6)" ::: "memory")
#define VM0 asm volatile("s_waitcnt vmcnt(0)" ::: "memory")

    // ---- prologue: tile0 (A0,B0,B1,A1) + tile1 (A0,B0,B1) ----
    STA(0, 0, 0); STB(0, 0, 0); STB(0, 1, 0); STA(0, 1, 0);
    STA(1, 0, 1); STB(1, 0, 1); STB(1, 1, 1);
    VM6;            // first 4 half-tiles (tile0) arrived
    BAR;

    constexpr int NT = D_ / 64;       // 32 K-tiles
    for (int i = 0; i < NT / 2 - 1; i++) {
        const int T = 2 * i;
        // P1
        RD_A(0, 0); RD_B(0, 0); STA(1, 1, T + 1);
        BAR; LGKM; MFMA_Q(0, 0); BAR;
        // P2
        RD_B(1, 0); STA(0, 0, T + 2);
        BAR; LGKM; MFMA_Q(0, 1); BAR;
        // P3
        RD_A(1, 0); STB(0, 0, T + 2);
        BAR; LGKM; MFMA_Q(1, 0); BAR;
        // P4
        STB(0, 1, T + 2);
        VM6; BAR; MFMA_Q(1, 1); BAR;
        // P5
        RD_A(0, 1); RD_B(0, 1); STA(0, 1, T + 2);
        BAR; LGKM; MFMA_Q(0, 0); BAR;
        // P6
        RD_B(1, 1); STA(1, 0, T + 3);
        BAR; LGKM; MFMA_Q(0, 1); BAR;
        // P7
        RD_A(1, 1); STB(1, 0, T + 3);
        BAR; LGKM; MFMA_Q(1, 0); BAR;
        // P8
        STB(1, 1, T + 3);
        VM6; BAR; MFMA_Q(1, 1); BAR;
    }
    // ---- peeled final iteration (T = NT-2): only the A1(NT-1) stage remains ----
    {
        RD_A(0, 0); RD_B(0, 0); STA(1, 1, NT - 1);
        BAR; LGKM; MFMA_Q(0, 0); BAR;
        RD_B(1, 0);
        BAR; LGKM; MFMA_Q(0, 1); BAR;
        RD_A(1, 0);
        BAR; LGKM; MFMA_Q(1, 0); BAR;
        VM0; BAR; MFMA_Q(1, 1); BAR;
        RD_A(0, 1); RD_B(0, 1);
        BAR; LGKM; MFMA_Q(0, 0); BAR;
        RD_B(1, 1);
        BAR; LGKM; MFMA_Q(0, 1); BAR;
        RD_A(1, 1);
        BAR; LGKM; MFMA_Q(1, 0); BAR;
        BAR; MFMA_Q(1, 1); BAR;
    }

    // ================= epilogue =================
    const int rb = (lane >> 4) * 4;
    const bool second = bn >= (NBN / 2);
    if (MODE == 1) {
        // transpose each 128(s) x 128(d) quadrant via LDS, store [bh][d][s]
        unsigned short* TT = lds;             // 128*136 shorts
        const int b = row0 >> 12;
        #pragma unroll
        for (int qd = 0; qd < 4; qd++) {
            const int sq = qd >> 1, dh = qd & 1;
            __syncthreads();
            if (wr == sq && (wc >> 1) == dh) {
                #pragma unroll
                for (int m = 0; m < 8; m++) {
                    #pragma unroll
                    for (int n = 0; n < 4; n++) {
                        float x0 = acc[m][n][0], x1 = acc[m][n][1];
                        float x2 = acc[m][n][2], x3 = acc[m][n][3];
                        if (!second) {
                            x0 = featmap(x0); x1 = featmap(x1);
                            x2 = featmap(x2); x3 = featmap(x3);
                        }
                        const int dcol = (wc & 1) * 64 + n * 16 + lr;
                        *(unsigned long long*)&TT[dcol * 136 + m * 16 + rb]
                            = pack4(x0, x1, x2, x3);
                    }
                }
            }
            __syncthreads();
            const int h2 = (bn & 7) * 2 + dh;
            const int s0 = (row0 + sq * 128) & (S_ - 1);
            unsigned short* dst = (second ? C2 : C1) + (size_t)(b * H_ + h2) * HD_ * S_;
            #pragma unroll
            for (int it = 0; it < 4; it++) {
                const int idx = it * 512 + tid;
                const int d = idx >> 4, sc2 = (idx & 15) * 8;
                *(u32x4*)&dst[(size_t)d * S_ + s0 + sc2] = *(const u32x4*)&TT[d * 136 + sc2];
            }
        }
        return;
    }
    #pragma unroll
    for (int m = 0; m < 8; m++) {
        #pragma unroll
        for (int n = 0; n < 4; n++) {
            #pragma unroll
            for (int r = 0; r < 4; r++) {
                const size_t gr = (size_t)(row0 + wr * 128 + m * 16 + rb + r);
                const int gc = bcol + wc * 64 + n * 16 + lr;
                float x = acc[m][n][r];
                if (MODE == 0) {
                    if (!second) {
                        C1[gr * D_ + gc] = f2bf(featmap(x));
                    } else {
                        const int gc2 = gc - D_;
                        float t = x + bias[gc2];
                        C2[gr * D_ + gc2] = f2bf(1.f / (1.f + __expf(-t)));
                    }
                } else {
                    Cf[gr * D_ + gc] = x;
                }
            }
        }
    }
#undef STA
#undef STB
#undef RD_A
#undef RD_B
#undef MFMA_Q
#undef BAR
#undef LGKM
#undef VM6
#undef VM0
}

// kv_summary partials: per (s-chunk cx, bh): part[cx][bh][d][e] = sum_s k[s,d]*v[s,e]
__global__ __launch_bounds__(256) void kvsum_part(
    const unsigned short* __restrict__ kT, const unsigned short* __restrict__ vT,
    float* __restrict__ part, float* __restrict__ ksum_part)
{
    __shared__ unsigned short kA[HD_ * LDSS];
    __shared__ unsigned short vB[HD_ * LDSS];
    __shared__ float red[HD_ * 8];
    const int tid = threadIdx.x;
    const int cx = blockIdx.x, bh = blockIdx.y;
    const int lane = tid & 63, w = tid >> 6;
    const int wm = (w >> 1) * 64, wn = (w & 1) * 64;
    const int lr = lane & 15, lk = (lane >> 4) * 8;
    const unsigned short* kb = kT + (size_t)bh * HD_ * S_;
    const unsigned short* vb = vT + (size_t)bh * HD_ * S_;
    f32x4 acc[4][4] = {};
    float ksl[4] = {0.f, 0.f, 0.f, 0.f};
    const int chunk = S_ / 8;
    const int s_begin = cx * chunk;
    for (int s0 = s_begin; s0 < s_begin + chunk; s0 += 64) {
        #pragma unroll
        for (int i = 0; i < 4; i++) {
            int idx = tid + i * 256;
            int d = idx >> 3, sc = (idx & 7) * 8;
            u32x4 kk = *(const u32x4*)&kb[(size_t)d * S_ + s0 + sc];
            *(u32x4*)&kA[d * LDSS + sc] = kk;
            unsigned short t8[8];
            *(u32x4*)t8 = kk;
            float ss = 0.f;
            #pragma unroll
            for (int j = 0; j < 8; j++) ss += bf2f(t8[j]);
            ksl[i] += ss;
            *(u32x4*)&vB[d * LDSS + sc] = *(const u32x4*)&vb[(size_t)d * S_ + s0 + sc];
        }
        __syncthreads();
        #pragma unroll
        for (int ks = 0; ks < 64; ks += 32) {
            bf16x8 av[4], bv[4];
            #pragma unroll
            for (int mi = 0; mi < 4; mi++)
                av[mi] = *(const bf16x8*)&kA[(wm + mi * 16 + lr) * LDSS + ks + lk];
            #pragma unroll
            for (int ni = 0; ni < 4; ni++)
                bv[ni] = *(const bf16x8*)&vB[(wn + ni * 16 + lr) * LDSS + ks + lk];
            #pragma unroll
            for (int mi = 0; mi < 4; mi++)
                #pragma unroll
                for (int ni = 0; ni < 4; ni++)
                    acc[mi][ni] = __builtin_amdgcn_mfma_f32_16x16x32_bf16(
                        av[mi], bv[ni], acc[mi][ni], 0, 0, 0);
        }
        __syncthreads();
    }
    #pragma unroll
    for (int i = 0; i < 4; i++) red[((tid >> 3) + 32 * i) * 8 + (tid & 7)] = ksl[i];
    __syncthreads();
    if (tid < HD_) {
        float s = 0.f;
        #pragma unroll
        for (int j = 0; j < 8; j++) s += red[tid * 8 + j];
        ksum_part[(size_t)cx * (64 * HD_) + bh * HD_ + tid] = s;
    }
    const int rb = (lane >> 4) * 4;
    float* pp = part + ((size_t)cx * 64 + bh) * (HD_ * HD_);
    #pragma unroll
    for (int mi = 0; mi < 4; mi++)
        #pragma unroll
        for (int ni = 0; ni < 4; ni++)
            #pragma unroll
            for (int r = 0; r < 4; r++)
                pp[(wm + mi * 16 + rb + r) * HD_ + wn + ni * 16 + lr] = acc[mi][ni][r];
}

__global__ __launch_bounds__(256) void kvs_reduce(
    const float* __restrict__ part, unsigned short* __restrict__ kvsT,
    const float* __restrict__ ksum_part, float* __restrict__ ksum)
{
    const int idx = blockIdx.x * 256 + threadIdx.x;
    const int e = idx & 127, d2 = (idx >> 7) & 127, bh = idx >> 14;
    float s = 0.f;
    #pragma unroll
    for (int cx = 0; cx < 8; cx++)
        s += part[((size_t)cx * 64 + bh) * 16384 + d2 * 128 + e];
    kvsT[((size_t)bh * 128 + e) * 128 + d2] = f2bf(s);
    if (idx < 64 * 128) {
        float t = 0.f;
        #pragma unroll
        for (int cx = 0; cx < 8; cx++) t += ksum_part[cx * 8192 + idx];
        ksum[idx] = t;
    }
}

// attn = (q @ kvs) * z * gate -> y (bf16)
__global__ __launch_bounds__(256) void attn_kernel(
    const unsigned short* __restrict__ qf, const unsigned short* __restrict__ kvsT,
    const float* __restrict__ ksum, const unsigned short* __restrict__ gate,
    unsigned short* __restrict__ y)
{
    __shared__ unsigned short qs[128 * 136];
    __shared__ unsigned short bs[128 * LDSS];
    __shared__ float zl[128];
    const int tid = threadIdx.x;
    const int l0 = blockIdx.x * 128;
    const int h = blockIdx.y, b = blockIdx.z;
    const int bh = b * H_ + h;
    const int lane = tid & 63, w = tid >> 6;
    const int wm = (w >> 1) * 64, wn = (w & 1) * 64;
    const int lr = lane & 15, lk = (lane >> 4) * 8;
    const size_t qbase = (size_t)b * L_ * D_ + (size_t)h * HD_;
    #pragma unroll
    for (int i = 0; i < 8; i++) {
        int idx = tid + i * 256;
        int r = idx >> 4, c = (idx & 15) * 8;
        *(u32x4*)&qs[r * 136 + c] = *(const u32x4*)&qf[qbase + (size_t)(l0 + r) * D_ + c];
    }
    __syncthreads();
    if (tid < 128) {
        const float* kp = ksum + bh * HD_;
        float sden = 0.f;
        #pragma unroll 4
        for (int d2 = 0; d2 < HD_; d2++) sden += bf2f(qs[tid * 136 + d2]) * kp[d2];
        zl[tid] = 1.f / (sden + 1e-6f);
    }
    f32x4 acc[4][4] = {};
    for (int kc = 0; kc < 2; kc++) {
        #pragma unroll
        for (int i = 0; i < 4; i++) {
            int idx = tid + i * 256;
            int e = idx >> 3, dc = (idx & 7) * 8;
            *(u32x4*)&bs[e * LDSS + dc] =
                *(const u32x4*)&kvsT[((size_t)bh * 128 + e) * 128 + kc * 64 + dc];
        }
        __syncthreads();
        #pragma unroll
        for (int ks = 0; ks < 64; ks += 32) {
            bf16x8 av[4], bv[4];
            #pragma unroll
            for (int mi = 0; mi < 4; mi++)
                av[mi] = *(const bf16x8*)&qs[(wm + mi * 16 + lr) * 136 + kc * 64 + ks + lk];
            #pragma unroll
            for (int ni = 0; ni < 4; ni++)
                bv[ni] = *(const bf16x8*)&bs[(wn + ni * 16 + lr) * LDSS + ks + lk];
            #pragma unroll
            for (int mi = 0; mi < 4; mi++)
                #pragma unroll
                for (int ni = 0; ni < 4; ni++)
                    acc[mi][ni] = __builtin_amdgcn_mfma_f32_16x16x32_bf16(
                        av[mi], bv[ni], acc[mi][ni], 0, 0, 0);
        }
        __syncthreads();
    }
    const int rb = (lane >> 4) * 4;
    #pragma unroll
    for (int mi = 0; mi < 4; mi++) {
        #pragma unroll
        for (int ni = 0; ni < 4; ni++) {
            #pragma unroll
            for (int r = 0; r < 4; r++) {
                int ll = wm + mi * 16 + rb + r;
                int e = wn + ni * 16 + lr;
                float attn = acc[mi][ni][r] * zl[ll];
                float g = bf2f(gate[qbase + (size_t)(l0 + ll) * D_ + e]);
                y[qbase + (size_t)(l0 + ll) * D_ + e] = f2bf(attn * g);
            }
        }
    }
}

extern "C" void kernel_launch(void* const* d_in, const int* in_sizes, int n_in,
                              void* d_out, int out_size, void* d_ws, size_t ws_size,
                              hipStream_t stream)
{
    (void)in_sizes; (void)n_in; (void)out_size; (void)ws_size;
    const float* query = (const float*)d_in[0];
    const float* kv    = (const float*)d_in[1];
    const float* Wq    = (const float*)d_in[2];
    const float* Wg    = (const float*)d_in[3];
    const float* bg    = (const float*)d_in[4];
    const float* Wkv   = (const float*)d_in[5];
    const float* Wo    = (const float*)d_in[6];
    float* out = (float*)d_out;
    char* ws = (char*)d_ws;

    // workspace layout (bytes). Region R is time-shared (stream-ordered).
    unsigned short* q_feat = (unsigned short*)(ws);                 // 64 MiB
    unsigned short* gate   = (unsigned short*)(ws + 67108864);      // 64 MiB
    unsigned short* kTb    = (unsigned short*)(ws + 134217728);     // 64 MiB [bh][d][s]
    unsigned short* vTb    = (unsigned short*)(ws + 201326592);     // 64 MiB [bh][d][s]
    char* R = ws + 268435456;
    unsigned short* qbf    = (unsigned short*)(R);                  // 64 MiB (phase1)
    unsigned short* Wqg    = (unsigned short*)(R + 67108864);       // 16 MiB (phase1)
    unsigned short* kvbf   = (unsigned short*)(R);                  // 64 MiB (phase2)
    unsigned short* Wkvb   = (unsigned short*)(R + 67108864);       // 16 MiB (phase2)
    float* part            = (float*)(R);                           // 32 MiB (phase3)
    float* ksum_part       = (float*)(R + 33554432);                // 256 KiB
    float* ksum            = (float*)(R + 33816576);                // 32 KiB
    unsigned short* kvsT   = (unsigned short*)(R + 33849344);       // 2 MiB
    unsigned short* Wob    = (unsigned short*)(R + 83886080);       // 8 MiB
    unsigned short* ybuf   = kTb;   // kT dead after kvsum_part

    dim3 blk(256, 1, 1);
    dim3 blk512(512, 1, 1);
    // ---- phase 1: q path ----
    cvt_bf16<<<dim3(2048), blk, 0, stream>>>(query, qbf, 4194304);
    cvt_bf16<<<dim3(2048), blk, 0, stream>>>(Wq, Wqg, 524288);
    cvt_bf16<<<dim3(2048), blk, 0, stream>>>(Wg, Wqg + 4194304, 524288);
    cvt_bf16<<<dim3(2048), blk, 0, stream>>>(Wo, Wob, 524288);
    gemm256<0, 16><<<dim3(1024), blk512, 0, stream>>>(qbf, Wqg, q_feat, gate, nullptr, bg);
    // ---- phase 2: kv path ----
    cvt_bf16<<<dim3(2048), blk, 0, stream>>>(kv, kvbf, 4194304);
    cvt_bf16<<<dim3(2048), blk, 0, stream>>>(Wkv, Wkvb, 1048576);
    gemm256<1, 16><<<dim3(1024), blk512, 0, stream>>>(kvbf, Wkvb, kTb, vTb, nullptr, nullptr);
    // ---- phase 3: summary + attention ----
    kvsum_part<<<dim3(8, 64), blk, 0, stream>>>(kTb, vTb, part, ksum_part);
    kvs_reduce<<<dim3(4096), blk, 0, stream>>>(part, kvsT, ksum_part, ksum);
    attn_kernel<<<dim3(32, 16, 4), blk, 0, stream>>>(q_feat, kvsT, ksum, gate, ybuf);
    // ---- output projection ----
    gemm256<2, 8><<<dim3(512), blk512, 0, stream>>>(ybuf, Wob, nullptr, nullptr, out, nullptr);
}

// Round 7
// 986.736 us; speedup vs baseline: 1.6248x; 1.0010x over previous
//
#include <hip/hip_runtime.h>

typedef __attribute__((ext_vector_type(8))) short bf16x8;
typedef __attribute__((ext_vector_type(4))) float f32x4;
typedef __attribute__((ext_vector_type(4))) unsigned int u32x4;

constexpr int L_ = 4096, S_ = 4096, D_ = 2048, H_ = 16, HD_ = 128;
constexpr int LDSS = 72; // padded stride for the small kernels

__device__ __forceinline__ unsigned short f2bf(float f) {
    unsigned int u = __builtin_bit_cast(unsigned int, f);
    return (unsigned short)((u + 0x7fffu + ((u >> 16) & 1u)) >> 16);
}
__device__ __forceinline__ float bf2f(unsigned short h) {
    unsigned int u = ((unsigned int)h) << 16;
    return __builtin_bit_cast(float, u);
}
__device__ __forceinline__ unsigned long long pack4(float a, float b, float c, float d) {
    return (unsigned long long)f2bf(a) | ((unsigned long long)f2bf(b) << 16)
         | ((unsigned long long)f2bf(c) << 32) | ((unsigned long long)f2bf(d) << 48);
}
__device__ __forceinline__ float featmap(float x) {
    return x > 0.f ? x + 1.f : __expf(x);
}
__device__ __forceinline__ void gload16(const unsigned short* g, unsigned short* l) {
    __builtin_amdgcn_global_load_lds(
        (const __attribute__((address_space(1))) void*)g,
        (__attribute__((address_space(3))) void*)l, 16, 0, 0);
}

// fp32 -> bf16 bulk convert
__global__ __launch_bounds__(256) void cvt_bf16(
    const float* __restrict__ in, unsigned short* __restrict__ out, int n8)
{
    const int stride = gridDim.x * 256;
    for (int i = blockIdx.x * 256 + threadIdx.x; i < n8; i += stride) {
        const float4 a = ((const float4*)in)[2 * i];
        const float4 b = ((const float4*)in)[2 * i + 1];
        unsigned long long* o = (unsigned long long*)&out[(size_t)i * 8];
        o[0] = pack4(a.x, a.y, a.z, a.w);
        o[1] = pack4(b.x, b.y, b.z, b.w);
    }
}

// ===================== 256x256 4-phase GEMM (T2+T3+T4+T5) =====================
// C = A @ B^T, A bf16 [M][2048], B bf16 [Ncols][2048]. K=2048, BK=64, 2 K-tiles/iter.
// 8 waves (2 wr x 4 wc), per-wave C = 128x64. LDS 128KiB double-buffered.
// Reads are plain C++ loads -> compiler emits fine-grained counted lgkmcnt per MFMA
// consumer. Read-ahead of next-buffer B0 sits BETWEEN Q(1,0) and Q(1,1): bv01 is
// consumed by Q(1,0) and dead during Q(1,1) (R6 bug: read-ahead before Q(1,0)
// clobbered its operand). sched_barrier(0) after each MFMA cluster pins the
// cluster inside its phase (WAR safety across the end-of-phase barrier).
// vmcnt(6) once per K-tile (counted, never 0 in the loop); each VM6 retires
// exactly one complete K-tile ({f,g,h,a} or {b,c,d,e}).
template<int MODE, int NBN>
__global__ __launch_bounds__(512, 2) void gemm256(
    const unsigned short* __restrict__ A, const unsigned short* __restrict__ B,
    unsigned short* __restrict__ C1, unsigned short* __restrict__ C2,
    float* __restrict__ Cf, const float* __restrict__ bias)
{
    __shared__ alignas(16) unsigned short lds[65536];   // 128 KiB
    const int tid = threadIdx.x;
    const int lane = tid & 63, w = tid >> 6;
    const int wr = w >> 2, wc = w & 3;
    const int lr = lane & 15;
    const int lk8 = (lane >> 4) * 8;          // K-element offset within 32-group
    const int rsw = (lr & 7) << 3;            // read-side swizzle (shorts)
    const int lsub = lane >> 3;               // 0..7
    const int scol = ((lane & 7) ^ lsub) * 8; // pre-swizzled source col (elements)

    // bijective XCD swizzle (nwg % 8 == 0 for all our grids)
    const int nwg = gridDim.x;
    const int wg = blockIdx.x;
    const int swz = (wg & 7) * (nwg >> 3) + (wg >> 3);
    const int bm = swz / NBN, bn = swz % NBN;
    const int row0 = bm * 256, bcol = bn * 256;

    const unsigned short* Ap = A + (size_t)row0 * D_;
    const unsigned short* Bp = B + (size_t)bcol * D_;
    const int rA = w * 8 + lsub;                              // A stage row (r=0)
    const int rB = ((w * 8 + lsub) >> 5) * 64 + ((w * 8 + lsub) & 31); // B stage row base

    f32x4 acc[8][4] = {};
    bf16x8 av[2][4], bv[2][4];

#define STA(BUF, HH, KT) do { \
    const unsigned short* g_ = Ap + (size_t)((HH) * 64 + rA) * D_ + (KT) * 64 + scol; \
    unsigned short* l_ = &lds[(BUF) * 16384 + (HH) * 8192 + w * 512]; \
    gload16(g_, l_); gload16(g_ + (size_t)128 * D_, l_ + 4096); } while (0)

#define STB(BUF, HH, KT) do { \
    const unsigned short* g_ = Bp + (size_t)(rB + (HH) * 32) * D_ + (KT) * 64 + scol; \
    unsigned short* l_ = &lds[32768 + (BUF) * 16384 + (HH) * 8192 + w * 512]; \
    gload16(g_, l_); gload16(g_ + (size_t)128 * D_, l_ + 4096); } while (0)

#define RD_A(MQ, BUF) \
    _Pragma("unroll") for (int mi = 0; mi < 4; mi++) \
    _Pragma("unroll") for (int ks = 0; ks < 2; ks++) \
        av[ks][mi] = *(const bf16x8*)&lds[(BUF) * 16384 + (MQ) * 8192 \
            + (mi * 16 + lr + wr * 64) * 64 + ((ks * 32 + lk8) ^ rsw)];

#define RD_B(NQ, BUF) \
    _Pragma("unroll") for (int j = 0; j < 2; j++) \
    _Pragma("unroll") for (int ks = 0; ks < 2; ks++) \
        bv[ks][(NQ) * 2 + j] = *(const bf16x8*)&lds[32768 + (BUF) * 16384 + (NQ) * 8192 \
            + (j * 16 + lr + wc * 32) * 64 + ((ks * 32 + lk8) ^ rsw)];

#define MFMA_Q(MQ, NQ) \
    _Pragma("unroll") for (int mi = 0; mi < 4; mi++) \
    _Pragma("unroll") for (int j = 0; j < 2; j++) \
    _Pragma("unroll") for (int ks = 0; ks < 2; ks++) \
        acc[(MQ) * 4 + mi][(NQ) * 2 + j] = __builtin_amdgcn_mfma_f32_16x16x32_bf16( \
            av[ks][mi], bv[ks][(NQ) * 2 + j], acc[(MQ) * 4 + mi][(NQ) * 2 + j], 0, 0, 0);

#define PRIO1 __builtin_amdgcn_s_setprio(1)
#define PRIO0 __builtin_amdgcn_s_setprio(0)
#define SB0 __builtin_amdgcn_sched_barrier(0)
#define BAR __builtin_amdgcn_s_barrier()
#define VM6 asm volatile("s_waitcnt vmcnt(6)" ::: "memory")
#define VM0 asm volatile("s_waitcnt vmcnt(0)" ::: "memory")

    // ---- prologue: tile0 (A0,B0,B1,A1) + tile1 (A0,B0,B1) ----
    STA(0, 0, 0); STB(0, 0, 0); STB(0, 1, 0); STA(0, 1, 0);
    STA(1, 0, 1); STB(1, 0, 1); STB(1, 1, 1);
    VM6;            // tile0's 4 half-tiles arrived (retires 8 oldest loads)
    BAR;
    RD_B(0, 0);     // bv01 <- B0 buf0 (one phase ahead)

    constexpr int NT = D_ / 64;       // 32 K-tiles
    for (int i = 0; i < NT / 2 - 1; i++) {
        const int T = 2 * i;
        // PH_A(buf0): av<-A0, bv23<-B1; Q(0,0)+Q(0,1)
        RD_A(0, 0); RD_B(1, 0);
        STA(1, 1, T + 1);                       // a
        BAR;
        PRIO1; MFMA_Q(0, 0); MFMA_Q(0, 1); PRIO0;
        SB0;
        BAR;
        // PH_B(buf0): av<-A1; Q(1,0); read-ahead bv01(buf1); Q(1,1)
        RD_A(1, 0);
        STA(0, 0, T + 2);                       // b
        STB(0, 0, T + 2);                       // c
        STB(0, 1, T + 2);                       // d
        VM6; BAR;                               // retires f,g,h(prev),a = tile T+1
        PRIO1; MFMA_Q(1, 0); PRIO0;             // consumes bv01 (B0 tile T)
        RD_B(0, 1);                             // bv01 <- B0 buf1 (tile T+1) — now dead
        PRIO1; MFMA_Q(1, 1); PRIO0;
        SB0;
        BAR;
        // PH_A(buf1)
        RD_A(0, 1); RD_B(1, 1);
        STA(0, 1, T + 2);                       // e
        BAR;
        PRIO1; MFMA_Q(0, 0); MFMA_Q(0, 1); PRIO0;
        SB0;
        BAR;
        // PH_B(buf1)
        RD_A(1, 1);
        STA(1, 0, T + 3);                       // f
        STB(1, 0, T + 3);                       // g
        STB(1, 1, T + 3);                       // h
        VM6; BAR;                               // retires b,c,d,e = tile T+2
        PRIO1; MFMA_Q(1, 0); PRIO0;             // consumes bv01 (B0 tile T+1)
        RD_B(0, 0);                             // bv01 <- B0 buf0 (tile T+2) — now dead
        PRIO1; MFMA_Q(1, 1); PRIO0;
        SB0;
        BAR;
    }
    // ---- peeled final iteration (T = NT-2): only the A1(NT-1) stage remains ----
    {
        RD_A(0, 0); RD_B(1, 0);
        STA(1, 1, NT - 1);                      // a
        BAR;
        PRIO1; MFMA_Q(0, 0); MFMA_Q(0, 1); PRIO0;
        SB0;
        BAR;
        RD_A(1, 0);
        VM0; BAR;                               // drain f,g,h(prev) + a
        PRIO1; MFMA_Q(1, 0); PRIO0;
        RD_B(0, 1);
        PRIO1; MFMA_Q(1, 1); PRIO0;
        SB0;
        BAR;
        RD_A(0, 1); RD_B(1, 1);
        BAR;
        PRIO1; MFMA_Q(0, 0); MFMA_Q(0, 1); PRIO0;
        SB0;
        BAR;
        RD_A(1, 1);
        BAR;
        PRIO1; MFMA_Q(1, 0); MFMA_Q(1, 1); PRIO0;  // bv01 = B0b1 (tile NT-1), untouched
        SB0;
        BAR;
    }

    // ================= epilogue =================
    const int rb = (lane >> 4) * 4;
    const bool second = bn >= (NBN / 2);
    if (MODE == 1) {
        // transpose each 128(s) x 128(d) quadrant via LDS, store [bh][d][s]
        unsigned short* TT = lds;             // 128*136 shorts
        const int b = row0 >> 12;
        #pragma unroll
        for (int qd = 0; qd < 4; qd++) {
            const int sq = qd >> 1, dh = qd & 1;
            __syncthreads();
            if (wr == sq && (wc >> 1) == dh) {
                #pragma unroll
                for (int m = 0; m < 8; m++) {
                    #pragma unroll
                    for (int n = 0; n < 4; n++) {
                        float x0 = acc[m][n][0], x1 = acc[m][n][1];
                        float x2 = acc[m][n][2], x3 = acc[m][n][3];
                        if (!second) {
                            x0 = featmap(x0); x1 = featmap(x1);
                            x2 = featmap(x2); x3 = featmap(x3);
                        }
                        const int dcol = (wc & 1) * 64 + n * 16 + lr;
                        *(unsigned long long*)&TT[dcol * 136 + m * 16 + rb]
                            = pack4(x0, x1, x2, x3);
                    }
                }
            }
            __syncthreads();
            const int h2 = (bn & 7) * 2 + dh;
            const int s0 = (row0 + sq * 128) & (S_ - 1);
            unsigned short* dst = (second ? C2 : C1) + (size_t)(b * H_ + h2) * HD_ * S_;
            #pragma unroll
            for (int it = 0; it < 4; it++) {
                const int idx = it * 512 + tid;
                const int d = idx >> 4, sc2 = (idx & 15) * 8;
                *(u32x4*)&dst[(size_t)d * S_ + s0 + sc2] = *(const u32x4*)&TT[d * 136 + sc2];
            }
        }
        return;
    }
    #pragma unroll
    for (int m = 0; m < 8; m++) {
        #pragma unroll
        for (int n = 0; n < 4; n++) {
            #pragma unroll
            for (int r = 0; r < 4; r++) {
                const size_t gr = (size_t)(row0 + wr * 128 + m * 16 + rb + r);
                const int gc = bcol + wc * 64 + n * 16 + lr;
                float x = acc[m][n][r];
                if (MODE == 0) {
                    if (!second) {
                        C1[gr * D_ + gc] = f2bf(featmap(x));
                    } else {
                        const int gc2 = gc - D_;
                        float t = x + bias[gc2];
                        C2[gr * D_ + gc2] = f2bf(1.f / (1.f + __expf(-t)));
                    }
                } else {
                    Cf[gr * D_ + gc] = x;
                }
            }
        }
    }
#undef STA
#undef STB
#undef RD_A
#undef RD_B
#undef MFMA_Q
#undef PRIO1
#undef PRIO0
#undef SB0
#undef BAR
#undef VM6
#undef VM0
}

// kv_summary partials: per (s-chunk cx, bh): part[cx][bh][d][e] = sum_s k[s,d]*v[s,e]
__global__ __launch_bounds__(256) void kvsum_part(
    const unsigned short* __restrict__ kT, const unsigned short* __restrict__ vT,
    float* __restrict__ part, float* __restrict__ ksum_part)
{
    __shared__ unsigned short kA[HD_ * LDSS];
    __shared__ unsigned short vB[HD_ * LDSS];
    __shared__ float red[HD_ * 8];
    const int tid = threadIdx.x;
    const int cx = blockIdx.x, bh = blockIdx.y;
    const int lane = tid & 63, w = tid >> 6;
    const int wm = (w >> 1) * 64, wn = (w & 1) * 64;
    const int lr = lane & 15, lk = (lane >> 4) * 8;
    const unsigned short* kb = kT + (size_t)bh * HD_ * S_;
    const unsigned short* vb = vT + (size_t)bh * HD_ * S_;
    f32x4 acc[4][4] = {};
    float ksl[4] = {0.f, 0.f, 0.f, 0.f};
    const int chunk = S_ / 8;
    const int s_begin = cx * chunk;
    for (int s0 = s_begin; s0 < s_begin + chunk; s0 += 64) {
        #pragma unroll
        for (int i = 0; i < 4; i++) {
            int idx = tid + i * 256;
            int d = idx >> 3, sc = (idx & 7) * 8;
            u32x4 kk = *(const u32x4*)&kb[(size_t)d * S_ + s0 + sc];
            *(u32x4*)&kA[d * LDSS + sc] = kk;
            unsigned short t8[8];
            *(u32x4*)t8 = kk;
            float ss = 0.f;
            #pragma unroll
            for (int j = 0; j < 8; j++) ss += bf2f(t8[j]);
            ksl[i] += ss;
            *(u32x4*)&vB[d * LDSS + sc] = *(const u32x4*)&vb[(size_t)d * S_ + s0 + sc];
        }
        __syncthreads();
        #pragma unroll
        for (int ks = 0; ks < 64; ks += 32) {
            bf16x8 av[4], bv[4];
            #pragma unroll
            for (int mi = 0; mi < 4; mi++)
                av[mi] = *(const bf16x8*)&kA[(wm + mi * 16 + lr) * LDSS + ks + lk];
            #pragma unroll
            for (int ni = 0; ni < 4; ni++)
                bv[ni] = *(const bf16x8*)&vB[(wn + ni * 16 + lr) * LDSS + ks + lk];
            #pragma unroll
            for (int mi = 0; mi < 4; mi++)
                #pragma unroll
                for (int ni = 0; ni < 4; ni++)
                    acc[mi][ni] = __builtin_amdgcn_mfma_f32_16x16x32_bf16(
                        av[mi], bv[ni], acc[mi][ni], 0, 0, 0);
        }
        __syncthreads();
    }
    #pragma unroll
    for (int i = 0; i < 4; i++) red[((tid >> 3) + 32 * i) * 8 + (tid & 7)] = ksl[i];
    __syncthreads();
    if (tid < HD_) {
        float s = 0.f;
        #pragma unroll
        for (int j = 0; j < 8; j++) s += red[tid * 8 + j];
        ksum_part[(size_t)cx * (64 * HD_) + bh * HD_ + tid] = s;
    }
    const int rb = (lane >> 4) * 4;
    float* pp = part + ((size_t)cx * 64 + bh) * (HD_ * HD_);
    #pragma unroll
    for (int mi = 0; mi < 4; mi++)
        #pragma unroll
        for (int ni = 0; ni < 4; ni++)
            #pragma unroll
            for (int r = 0; r < 4; r++)
                pp[(wm + mi * 16 + rb + r) * HD_ + wn + ni * 16 + lr] = acc[mi][ni][r];
}

__global__ __launch_bounds__(256) void kvs_reduce(
    const float* __restrict__ part, unsigned short* __restrict__ kvsT,
    const float* __restrict__ ksum_part, float* __restrict__ ksum)
{
    const int idx = blockIdx.x * 256 + threadIdx.x;
    const int e = idx & 127, d2 = (idx >> 7) & 127, bh = idx >> 14;
    float s = 0.f;
    #pragma unroll
    for (int cx = 0; cx < 8; cx++)
        s += part[((size_t)cx * 64 + bh) * 16384 + d2 * 128 + e];
    kvsT[((size_t)bh * 128 + e) * 128 + d2] = f2bf(s);
    if (idx < 64 * 128) {
        float t = 0.f;
        #pragma unroll
        for (int cx = 0; cx < 8; cx++) t += ksum_part[cx * 8192 + idx];
        ksum[idx] = t;
    }
}

// attn = (q @ kvs) * z * gate -> y (bf16)
__global__ __launch_bounds__(256) void attn_kernel(
    const unsigned short* __restrict__ qf, const unsigned short* __restrict__ kvsT,
    const float* __restrict__ ksum, const unsigned short* __restrict__ gate,
    unsigned short* __restrict__ y)
{
    __shared__ unsigned short qs[128 * 136];
    __shared__ unsigned short bs[128 * LDSS];
    __shared__ float zl[128];
    const int tid = threadIdx.x;
    const int l0 = blockIdx.x * 128;
    const int h = blockIdx.y, b = blockIdx.z;
    const int bh = b * H_ + h;
    const int lane = tid & 63, w = tid >> 6;
    const int wm = (w >> 1) * 64, wn = (w & 1) * 64;
    const int lr = lane & 15, lk = (lane >> 4) * 8;
    const size_t qbase = (size_t)b * L_ * D_ + (size_t)h * HD_;
    #pragma unroll
    for (int i = 0; i < 8; i++) {
        int idx = tid + i * 256;
        int r = idx >> 4, c = (idx & 15) * 8;
        *(u32x4*)&qs[r * 136 + c] = *(const u32x4*)&qf[qbase + (size_t)(l0 + r) * D_ + c];
    }
    __syncthreads();
    if (tid < 128) {
        const float* kp = ksum + bh * HD_;
        float sden = 0.f;
        #pragma unroll 4
        for (int d2 = 0; d2 < HD_; d2++) sden += bf2f(qs[tid * 136 + d2]) * kp[d2];
        zl[tid] = 1.f / (sden + 1e-6f);
    }
    f32x4 acc[4][4] = {};
    for (int kc = 0; kc < 2; kc++) {
        #pragma unroll
        for (int i = 0; i < 4; i++) {
            int idx = tid + i * 256;
            int e = idx >> 3, dc = (idx & 7) * 8;
            *(u32x4*)&bs[e * LDSS + dc] =
                *(const u32x4*)&kvsT[((size_t)bh * 128 + e) * 128 + kc * 64 + dc];
        }
        __syncthreads();
        #pragma unroll
        for (int ks = 0; ks < 64; ks += 32) {
            bf16x8 av[4], bv[4];
            #pragma unroll
            for (int mi = 0; mi < 4; mi++)
                av[mi] = *(const bf16x8*)&qs[(wm + mi * 16 + lr) * 136 + kc * 64 + ks + lk];
            #pragma unroll
            for (int ni = 0; ni < 4; ni++)
                bv[ni] = *(const bf16x8*)&bs[(wn + ni * 16 + lr) * LDSS + ks + lk];
            #pragma unroll
            for (int mi = 0; mi < 4; mi++)
                #pragma unroll
                for (int ni = 0; ni < 4; ni++)
                    acc[mi][ni] = __builtin_amdgcn_mfma_f32_16x16x32_bf16(
                        av[mi], bv[ni], acc[mi][ni], 0, 0, 0);
        }
        __syncthreads();
    }
    const int rb = (lane >> 4) * 4;
    #pragma unroll
    for (int mi = 0; mi < 4; mi++) {
        #pragma unroll
        for (int ni = 0; ni < 4; ni++) {
            #pragma unroll
            for (int r = 0; r < 4; r++) {
                int ll = wm + mi * 16 + rb + r;
                int e = wn + ni * 16 + lr;
                float attn = acc[mi][ni][r] * zl[ll];
                float g = bf2f(gate[qbase + (size_t)(l0 + ll) * D_ + e]);
                y[qbase + (size_t)(l0 + ll) * D_ + e] = f2bf(attn * g);
            }
        }
    }
}

extern "C" void kernel_launch(void* const* d_in, const int* in_sizes, int n_in,
                              void* d_out, int out_size, void* d_ws, size_t ws_size,
                              hipStream_t stream)
{
    (void)in_sizes; (void)n_in; (void)out_size; (void)ws_size;
    const float* query = (const float*)d_in[0];
    const float* kv    = (const float*)d_in[1];
    const float* Wq    = (const float*)d_in[2];
    const float* Wg    = (const float*)d_in[3];
    const float* bg    = (const float*)d_in[4];
    const float* Wkv   = (const float*)d_in[5];
    const float* Wo    = (const float*)d_in[6];
    float* out = (float*)d_out;
    char* ws = (char*)d_ws;

    // workspace layout (bytes). Region R is time-shared (stream-ordered).
    unsigned short* q_feat = (unsigned short*)(ws);                 // 64 MiB
    unsigned short* gate   = (unsigned short*)(ws + 67108864);      // 64 MiB
    unsigned short* kTb    = (unsigned short*)(ws + 134217728);     // 64 MiB [bh][d][s]
    unsigned short* vTb    = (unsigned short*)(ws + 201326592);     // 64 MiB [bh][d][s]
    char* R = ws + 268435456;
    unsigned short* qbf    = (unsigned short*)(R);                  // 64 MiB (phase1)
    unsigned short* Wqg    = (unsigned short*)(R + 67108864);       // 16 MiB (phase1)
    unsigned short* kvbf   = (unsigned short*)(R);                  // 64 MiB (phase2)
    unsigned short* Wkvb   = (unsigned short*)(R + 67108864);       // 16 MiB (phase2)
    float* part            = (float*)(R);                           // 32 MiB (phase3)
    float* ksum_part       = (float*)(R + 33554432);                // 256 KiB
    float* ksum            = (float*)(R + 33816576);                // 32 KiB
    unsigned short* kvsT   = (unsigned short*)(R + 33849344);       // 2 MiB
    unsigned short* Wob    = (unsigned short*)(R + 83886080);       // 8 MiB
    unsigned short* ybuf   = kTb;   // kT dead after kvsum_part

    dim3 blk(256, 1, 1);
    dim3 blk512(512, 1, 1);
    // ---- phase 1: q path ----
    cvt_bf16<<<dim3(2048), blk, 0, stream>>>(query, qbf, 4194304);
    cvt_bf16<<<dim3(2048), blk, 0, stream>>>(Wq, Wqg, 524288);
    cvt_bf16<<<dim3(2048), blk, 0, stream>>>(Wg, Wqg + 4194304, 524288);
    cvt_bf16<<<dim3(2048), blk, 0, stream>>>(Wo, Wob, 524288);
    gemm256<0, 16><<<dim3(1024), blk512, 0, stream>>>(qbf, Wqg, q_feat, gate, nullptr, bg);
    // ---- phase 2: kv path ----
    cvt_bf16<<<dim3(2048), blk, 0, stream>>>(kv, kvbf, 4194304);
    cvt_bf16<<<dim3(2048), blk, 0, stream>>>(Wkv, Wkvb, 1048576);
    gemm256<1, 16><<<dim3(1024), blk512, 0, stream>>>(kvbf, Wkvb, kTb, vTb, nullptr, nullptr);
    // ---- phase 3: summary + attention ----
    kvsum_part<<<dim3(8, 64), blk, 0, stream>>>(kTb, vTb, part, ksum_part);
    kvs_reduce<<<dim3(4096), blk, 0, stream>>>(part, kvsT, ksum_part, ksum);
    attn_kernel<<<dim3(32, 16, 4), blk, 0, stream>>>(q_feat, kvsT, ksum, gate, ybuf);
    // ---- output projection ----
    gemm256<2, 8><<<dim3(512), blk512, 0, stream>>>(ybuf, Wob, nullptr, nullptr, out, nullptr);
}